// Round 8
// baseline (10634.096 us; speedup 1.0000x reference)
//
#include <hip/hip_runtime.h>
#include <hip/hip_bf16.h>

#define BB 16
#define TT 16
#define CC 128
#define HW 1024             // 32*32
#define PIX (CC*HW)         // 131072
#define STOT ((long)BB*PIX) // 2M

// B-image geometry v2: tiles of 128 pixels x 32 k, KBLOCK-MAJOR, no pads.
// word(row, kw) = (kw>>2)*512 + phys(row,kb)*4 + (kw&3), phys = (row+16*kb)&127
#define BTW 4096            // u32 words per B tile
#define WI  131072          // u32 words per batch, K=128 image (8 p-tiles * 4 k-tiles)
#define WZ  262144          // u32 words per batch, K=256 image (ZHZM)
#define XW  2097152         // u32 words per timestep of Xp (16 batches * WI)
#define BIGI (1 << 30)
#define GRID 512

typedef short short8 __attribute__((ext_vector_type(8)));
typedef float f32x4  __attribute__((ext_vector_type(4)));

__device__ __forceinline__ float sigf(float x) { return 1.0f / (1.0f + __expf(-x)); }
__device__ __forceinline__ float tanhf_fast(float x) {
    float ax = fabsf(x);
    float t = __expf(-2.0f * ax);
    float r = (1.0f - t) / (1.0f + t);
    return copysignf(r, x);
}

// ---- packed hi/lo bf16: uint32 = (bf16(x)<<16) | bf16(x - bf16(x)) ----
__device__ __forceinline__ unsigned pack_hl(float x) {
    unsigned u = __float_as_uint(x);
    unsigned hi = (u + 0x7fffu + ((u >> 16) & 1u)) >> 16;
    float r = x - __uint_as_float(hi << 16);
    unsigned v = __float_as_uint(r);
    unsigned lo = (v + 0x7fffu + ((v >> 16) & 1u)) >> 16;
    return (hi << 16) | lo;
}
__device__ __forceinline__ float unpack_hl(unsigned p) {
    return __uint_as_float(p & 0xffff0000u) + __uint_as_float(p << 16);
}
__device__ __forceinline__ unsigned short pack_bf16(float x) {
    unsigned u = __float_as_uint(x);
    return (unsigned short)((u + 0x7fffu + ((u >> 16) & 1u)) >> 16);
}
__device__ __forceinline__ float bf16f(unsigned short s) {
    return __uint_as_float(((unsigned)s) << 16);
}

// B-side split (activations packed u32 in LDS)
__device__ __forceinline__ void split_frag(uint4 a, uint4 b, short8& hi, short8& lo) {
    unsigned w[8] = {a.x, a.y, a.z, a.w, b.x, b.y, b.z, b.w};
    union U { unsigned u[4]; short8 s; } h, l;
    #pragma unroll
    for (int j = 0; j < 4; ++j) {
        h.u[j] = (w[2*j] >> 16)      | (w[2*j+1] & 0xffff0000u);
        l.u[j] = (w[2*j] & 0xffffu)  | (w[2*j+1] << 16);
    }
    hi = h.s; lo = l.s;
}

// B tile addr v2 (u32 units): kblock-major + 16-row rotation per kblock
__device__ __forceinline__ int taddr2(int row, int kw) {
    int kb = kw >> 2;
    return (kb << 9) + (((row + (kb << 4)) & 127) << 2) + (kw & 3);
}
// word index of element (pixel p, k-channel c) in a per-batch image with nkt k-tiles
__device__ __forceinline__ long bwidx2(int p, int c, int nkt) {
    return ((long)((p >> 7) * nkt + (c >> 5)) << 12) + taddr2(p & 127, c & 31);
}

typedef __attribute__((address_space(3))) unsigned lds_u32_t;
typedef __attribute__((address_space(1))) const unsigned gbl_u32_t;
__device__ __forceinline__ void gld16(const void* g, unsigned* l) {
    __builtin_amdgcn_global_load_lds((gbl_u32_t*)g, (lds_u32_t*)l, 16, 0, 0);
}

// ---- per-batch spin barrier: 32 blocks, device-scope fence (XCD-safe) ----
__device__ __forceinline__ void gsync(unsigned* c, unsigned target) {
    __threadfence();                       // release this thread's writes (agent)
    __syncthreads();                       // all threads' fences done
    if (threadIdx.x == 0) {
        __hip_atomic_fetch_add(c, 1u, __ATOMIC_RELEASE, __HIP_MEMORY_SCOPE_AGENT);
        while (__hip_atomic_load(c, __ATOMIC_ACQUIRE, __HIP_MEMORY_SCOPE_AGENT) < target)
            __builtin_amdgcn_s_sleep(2);
    }
    __syncthreads();
    __threadfence();                       // acquire: invalidate before data reads
}

// ---------------- GEMM tile (device): dbuf pipeline, fused epilogues ----------------
// MODE 1: bf16 store (+ scalar bias[row]) -> outv ushort* linear
// MODE 2: LSTM fuse: stv=Cst f32 linear, outv=Ha image
// MODE 3: final fuse: stv=mp image, outv=Hb image, Hout opt fp32 linear
template<int MODE, int LO0>
__device__ __forceinline__ void gemm_tile(
    const unsigned* Wp, const float* bias,
    const unsigned* imgA, long wA,
    const unsigned* imgB, long wB, int nktB,
    int k_split, int m_split,
    void* outv, void* stv, float* Hout,
    int M, int K, int n0, int m0, int b,
    unsigned* As, unsigned* Bs)           // As: 2*5120, Bs: 2*4096 u32
{
    const int tix = threadIdx.x;
    const int lane = tix & 63;
    const int w  = tix >> 6;
    const int wm = w & 1, wn = w >> 1;
    const int g  = lane >> 4, pl = lane & 15;
    const int cb = ((g + (pl >> 2)) & 3) << 4;
    const int nk = K >> 5;

    f32x4 acc[4][4] = {};

    auto stage = [&](int k0, int buf) {
        const char* gA = (const char*)Wp +
            (size_t)((m0 >> 7) * nk + (k0 >> 5)) * 20480;
        #pragma unroll
        for (int r = 0; r < 5; ++r)
            gld16(gA + r * 4096 + tix * 16, As + buf * 5120 + r * 1024 + tix * 4);
        const bool useB = (m0 >= m_split) || (k0 >= k_split);
        const int kc = useB ? (k0 - ((m0 >= m_split) ? 0 : k_split)) : k0;
        const unsigned* img = useB ? imgB : imgA;
        const long bw = useB ? wB : wA;
        const int nkt = useB ? nktB : 4;
        const char* gB = (const char*)(img + (long)b * bw +
            ((long)((n0 >> 7) * nkt + (kc >> 5)) << 12));
        #pragma unroll
        for (int r = 0; r < 4; ++r)
            gld16(gB + r * 4096 + tix * 16, Bs + buf * 4096 + r * 1024 + tix * 4);
    };

    stage(0, 0);

    for (int ks = 0; ks < nk; ++ks) {
        const int buf = ks & 1;
        __syncthreads();                           // drains stage(ks)
        if (ks + 1 < nk) stage((ks + 1) << 5, buf ^ 1);

        short8 ahi[4], alo[4], bhi[4], blo[4];
        #pragma unroll
        for (int mt = 0; mt < 4; ++mt) {
            int row = 64 * wm + 16 * mt + pl;
            const char* pa = (const char*)(As + buf * 5120) + row * 80 + cb;
            ahi[mt] = *(const short8*)pa;
            alo[mt] = *(const short8*)(pa + 10240);
        }
        #pragma unroll
        for (int nt = 0; nt < 4; ++nt) {
            int prow = 64 * wn + 16 * nt + pl;
            uint4 w0 = *(const uint4*)(Bs + buf * 4096 + taddr2(prow, 8 * g));
            uint4 w1 = *(const uint4*)(Bs + buf * 4096 + taddr2(prow, 8 * g + 4));
            split_frag(w0, w1, bhi[nt], blo[nt]);
        }
        const bool useBc = (m0 >= m_split) || ((ks << 5) >= k_split);
        if (LO0 && useBc) {
            #pragma unroll
            for (int mt = 0; mt < 4; ++mt)
                #pragma unroll
                for (int nt = 0; nt < 4; ++nt) {
                    acc[mt][nt] = __builtin_amdgcn_mfma_f32_16x16x32_bf16(ahi[mt], bhi[nt], acc[mt][nt], 0, 0, 0);
                    acc[mt][nt] = __builtin_amdgcn_mfma_f32_16x16x32_bf16(alo[mt], bhi[nt], acc[mt][nt], 0, 0, 0);
                }
        } else {
            #pragma unroll
            for (int mt = 0; mt < 4; ++mt)
                #pragma unroll
                for (int nt = 0; nt < 4; ++nt) {
                    acc[mt][nt] = __builtin_amdgcn_mfma_f32_16x16x32_bf16(ahi[mt], bhi[nt], acc[mt][nt], 0, 0, 0);
                    acc[mt][nt] = __builtin_amdgcn_mfma_f32_16x16x32_bf16(ahi[mt], blo[nt], acc[mt][nt], 0, 0, 0);
                    acc[mt][nt] = __builtin_amdgcn_mfma_f32_16x16x32_bf16(alo[mt], bhi[nt], acc[mt][nt], 0, 0, 0);
                }
        }
    }

    if (MODE == 1) {
        #pragma unroll
        for (int mt = 0; mt < 4; ++mt)
            #pragma unroll
            for (int r = 0; r < 4; ++r) {
                int row = m0 + 64 * wm + 16 * mt + 4 * g + r;
                float bb = bias[row];
                #pragma unroll
                for (int nt = 0; nt < 4; ++nt) {
                    int col = n0 + 64 * wn + 16 * nt + pl;
                    ((unsigned short*)outv)[((long)b * M + row) * HW + col] =
                        pack_bf16(acc[mt][nt][r] + bb);
                }
            }
    } else {
        const float4* bias4 = (const float4*)bias;
        unsigned* Hp = (unsigned*)outv;
        #pragma unroll
        for (int mt = 0; mt < 4; ++mt) {
            int c = (m0 >> 2) + 16 * wm + 4 * mt + g;
            float4 bb = bias4[c];
            #pragma unroll
            for (int nt = 0; nt < 4; ++nt) {
                int p = n0 + 64 * wn + 16 * nt + pl;
                long lidx = (long)b * PIX + (long)c * HW + p;       // linear
                long widx = (long)b * WI + bwidx2(p, c, 4);         // image
                float v0 = acc[mt][nt][0] + bb.x;
                float v1 = acc[mt][nt][1] + bb.y;
                float v2 = acc[mt][nt][2] + bb.z;
                float v3 = acc[mt][nt][3] + bb.w;
                if (MODE == 2) {
                    float* Cst = (float*)stv;
                    float cc = Cst[lidx] * sigf(v0) + sigf(v1) * tanhf_fast(v2);
                    Cst[lidx] = cc;
                    Hp[widx] = pack_hl(sigf(v3) * tanhf_fast(cc));
                } else {
                    unsigned* mp = (unsigned*)stv;
                    float ot = sigf(v0), gt = tanhf_fast(v1), it = sigf(v2);
                    float mo = unpack_hl(mp[widx]);
                    float mn = gt * it + (1.0f - it) * mo;
                    mp[widx] = pack_hl(mn);
                    float hv = ot * mn;
                    Hp[widx] = pack_hl(hv);
                    if (Hout) Hout[lidx] = hv;
                }
            }
        }
    }
}

// ---------------- attention tile (device, 256 thr): 4 channels, all 1024 px ----------------
__device__ __forceinline__ void attn_tile(
    const unsigned short* VKM, unsigned* Zimg, int b, int cq, float* qsT)
{
    const int tid = threadIdx.x;
    const int c0 = cq << 2;
    const long base = (long)b * 640 * HW;
    #pragma unroll
    for (int cc = 0; cc < 4; ++cc)
        #pragma unroll
        for (int q = 0; q < 4; ++q) {
            int p = tid + (q << 8);
            qsT[cc * 1056 + (p & 31) * 33 + (p >> 5)] =
                bf16f(VKM[base + (long)(256 + c0 + cc) * HW + p]);
        }
    __syncthreads();
    const int kt = c0 >> 5, kb = (c0 & 31) >> 2;
    #pragma unroll
    for (int q = 0; q < 4; ++q) {
        int p = tid + (q << 8);
        uint4 oh, om;
        unsigned* ohw = (unsigned*)&oh;
        unsigned* omw = (unsigned*)&om;
        #pragma unroll
        for (int cc = 0; cc < 4; ++cc) {
            const long cbs = base + (long)(c0 + cc) * HW;
            float qhT = qsT[cc * 1056 + (p >> 5) * 33 + (p & 31)];
            float vh  = bf16f(VKM[cbs + p]);
            float kh  = bf16f(VKM[cbs + 128l * HW + p]);
            float km  = bf16f(VKM[cbs + 384l * HW + p]);
            float vm  = bf16f(VKM[cbs + 512l * HW + p]);
            float sh = kh * qhT, sm = qhT * km;
            float mh = sh, mm = sm;
            #pragma unroll
            for (int o = 16; o > 0; o >>= 1) {
                mh = fmaxf(mh, __shfl_xor(mh, o, 32));
                mm = fmaxf(mm, __shfl_xor(mm, o, 32));
            }
            float eh = __expf(sh - mh), em = __expf(sm - mm);
            float s1 = eh, s2 = em;
            #pragma unroll
            for (int o = 16; o > 0; o >>= 1) {
                s1 += __shfl_xor(s1, o, 32);
                s2 += __shfl_xor(s2, o, 32);
            }
            ohw[cc] = ((unsigned)pack_bf16(vh * (eh / s1))) << 16;
            omw[cc] = ((unsigned)pack_bf16(vm * (em / s2))) << 16;
        }
        const int phys = ((p & 127) + (kb << 4)) & 127;
        long u4 = ((long)b << 16) + ((long)(p >> 7) << 13) + (kb << 7) + phys;
        ((uint4*)Zimg)[u4 + ((long)kt << 10)]       = oh;
        ((uint4*)Zimg)[u4 + ((long)(kt + 4) << 10)] = om;
    }
    __syncthreads();
}

// ---------------- persistent mega-kernel: all 16 timesteps, 4 phases ----------------
// grid 512 = 2 blocks/CU exactly (LDS 73.7KB, launch_bounds(256,2)).
// bid mapping: batch b = ((bid&7)<<1)|((bid>>3)&1) (XCD-aligned under bid%8 mapping,
// speed-only), tile = bid>>4 in [0,32). Per-batch 32-block barriers.
__global__ __launch_bounds__(256, 2) void mega(
    const float* x,
    const unsigned* Wgi, const float* bg4,
    const unsigned* Wp5i, const float* b5,
    const unsigned* Woi, const float* bo4,
    unsigned* Xp, unsigned* Ha, unsigned* Hb, unsigned* mp, float* Cst,
    unsigned short* VKM, unsigned* Zimg, float* out, unsigned* cnt, int havex)
{
    __shared__ __align__(16) unsigned sh[2 * 5120 + 2 * 4096];  // 73728 B
    unsigned* As = sh;
    unsigned* Bs = sh + 2 * 5120;

    const int bid = blockIdx.x;
    const int b = ((bid & 7) << 1) | ((bid >> 3) & 1);
    const int tile = bid >> 4;
    const int n0 = (tile & 7) << 7, m0 = (tile >> 3) << 7;
    unsigned* cbar = cnt + b * 16;
    unsigned bar = 0;

    for (int t = 0; t < TT; ++t) {
        const unsigned* Xpt = Xp + (havex ? (long)t * XW : 0l);
        if (!havex) {
            // pack this batch's x_t image slice (1024 u4 per block)
            #pragma unroll
            for (int i = 0; i < 4; ++i) {
                int v = (tile << 10) + (i << 8) + (int)threadIdx.x;
                int pt = v >> 12, kt = (v >> 10) & 3;
                int ww = v & 1023, kb = ww >> 7, phys = ww & 127;
                int row = (phys - (kb << 4)) & 127;
                int p = (pt << 7) + row;
                int c = (kt << 5) + (kb << 2);
                const float* xs = x + (((long)b * TT + t) * CC + c) * HW + p;
                uint4 o;
                o.x = pack_hl(xs[0]);
                o.y = pack_hl(xs[HW]);
                o.z = pack_hl(xs[2 * HW]);
                o.w = pack_hl(xs[3 * HW]);
                ((uint4*)Xp)[(long)b * 32768 + v] = o;
            }
            bar++; gsync(cbar, bar * 32);
        }

        // G1: gates = Wg * [Hb ; x_t] -> Cst, Ha   (M=512, K=256)
        gemm_tile<2, 0>(Wgi, bg4, Hb, (long)WI, Xpt, (long)WI, 4,
                        128, BIGI, Ha, Cst, nullptr, 512, 256, n0, m0, b, As, Bs);
        bar++; gsync(cbar, bar * 32);

        // G2: vh,kh,qh (Ha) + km,vm (mp) -> VKM  (M=640, K=128); 8 blocks do 2 tiles
        for (int tt = tile; tt < 40; tt += 32)
            gemm_tile<1, 0>(Wp5i, b5, Ha, (long)WI, mp, (long)WI, 4,
                            BIGI, 384, VKM, nullptr, nullptr, 640, 128,
                            (tt & 7) << 7, (tt >> 3) << 7, b, As, Bs);
        bar++; gsync(cbar, bar * 32);

        // attention -> Zimg
        attn_tile(VKM, Zimg, b, tile, (float*)sh);
        bar++; gsync(cbar, bar * 32);

        // G3: o,g,i = Wo * [Ha ; Zimg] -> mp, Hb (+out at t=15)  (M=512, K=384)
        gemm_tile<3, 1>(Woi, bo4, Ha, (long)WI, Zimg, (long)WZ, 8,
                        128, BIGI, Hb, mp, (t == TT - 1) ? out : nullptr,
                        512, 384, n0, m0, b, As, Bs);
        bar++; gsync(cbar, bar * 32);
    }
}

// ---------------- pack x one-shot (dest-linear streaming, R6-proven) ----------------
__global__ __launch_bounds__(256) void pack_x(
    const float* __restrict__ x, uint4* __restrict__ Xp)
{
    long idx = (long)blockIdx.x * 256 + threadIdx.x;
    int t = (int)(idx >> 19);
    long rest = idx & ((1l << 19) - 1);
    int b = (int)(rest >> 15);
    int v = (int)(rest & 32767);
    int kb = (v >> 7) & 7, phys = v & 127;
    int row = (phys - (kb << 4)) & 127;
    int p = ((v >> 12) << 7) + row;
    int c = (((v >> 10) & 3) << 5) + (kb << 2);
    const float* xs = x + (((long)b * TT + t) * CC + c) * HW + p;
    uint4 o;
    o.x = pack_hl(xs[0]);
    o.y = pack_hl(xs[HW]);
    o.z = pack_hl(xs[2 * HW]);
    o.w = pack_hl(xs[3 * HW]);
    Xp[idx] = o;
}

// ---------------- one-shot setup: build pre-swizzled hi/lo weight tile images ----------------
__device__ __forceinline__ void wimg(unsigned short* img, int Ktiles, int r, int k, float v) {
    int tile = (r >> 7) * Ktiles + (k >> 5);
    int row = r & 127, ks = k & 31;
    unsigned short* p = img + (size_t)tile * 10240;
    int off = row * 40 + ((((ks >> 3) + (row >> 2)) & 3) << 3) + (ks & 7);
    unsigned u = __float_as_uint(v);
    unsigned short hi = (unsigned short)((u + 0x7fffu + ((u >> 16) & 1u)) >> 16);
    float rr = v - __uint_as_float((unsigned)hi << 16);
    unsigned u2 = __float_as_uint(rr);
    unsigned short lo = (unsigned short)((u2 + 0x7fffu + ((u2 >> 16) & 1u)) >> 16);
    p[off] = hi;
    p[off + 5120] = lo;
}

__global__ __launch_bounds__(256) void setup_all(
    const float* __restrict__ W5, const float* __restrict__ W8, const float* __restrict__ b8,
    unsigned short* __restrict__ Wp5i,
    unsigned short* __restrict__ Wgi, float* __restrict__ bg4,
    unsigned short* __restrict__ Woi, float* __restrict__ bo4)
{
    int idx = blockIdx.x * 256 + threadIdx.x;
    if (idx < 81920) {                       // W5 [640][128] -> Wp5 image
        int r = idx >> 7, k = idx & 127;
        wimg(Wp5i, 4, r, k, W5[idx]);
        return;
    }
    idx -= 81920;
    if (idx < 131072) {                      // Wg: rows c*4+gate, convs 10..13, K=256
        int rr = idx >> 8, k = idx & 255;
        int c = rr >> 2, gg = rr & 3;
        wimg(Wgi, 8, rr, k, W8[((long)(4 + gg) * 128 + c) * 256 + k]);
        if (k == 0) bg4[rr] = b8[(4 + gg) * 128 + c];
        return;
    }
    idx -= 131072;                           // Wo: 512 rows x 384, conv6 folded
    if (idx >= 512 * 384) return;
    int rr = idx / 384, k = idx - rr * 384;
    int c = rr >> 2, gg = rr & 3;
    float wv = 0.0f;
    if (gg < 3) {
        const float* wr = W8 + ((long)(1 + gg) * 128 + c) * 256;
        if (k < 128) {
            wv = wr[k];
        } else {
            int i = k - 128;
            float s = 0.0f;
            for (int j = 0; j < 128; ++j)
                s += wr[128 + j] * W8[(long)j * 256 + i];   // Wz = W8[0]
            wv = s;
        }
    }
    wimg(Woi, 12, rr, k, wv);
    if (k == 0) {
        float bb = 0.0f;
        if (gg < 3) {
            bb = b8[(1 + gg) * 128 + c];
            const float* wr = W8 + ((long)(1 + gg) * 128 + c) * 256;
            for (int j = 0; j < 128; ++j) bb += wr[128 + j] * b8[j];  // bz = b8[0]
        }
        bo4[rr] = bb;
    }
}

extern "C" void kernel_launch(void* const* d_in, const int* in_sizes, int n_in,
                              void* d_out, int out_size, void* d_ws, size_t ws_size,
                              hipStream_t stream)
{
    const float* x  = (const float*)d_in[0];   // [16][16][128][1024]  (B-major)
    const float* c0 = (const float*)d_in[1];
    const float* W5 = (const float*)d_in[2];   // [640][128]
    const float* b5 = (const float*)d_in[3];   // [640]
    const float* W8 = (const float*)d_in[4];   // [8][128][256]
    const float* b8 = (const float*)d_in[5];   // [8][128]
    float* out = (float*)d_out;

    const long S = STOT;
    unsigned* Ha   = (unsigned*)d_ws;                   // 16*WI (image)
    unsigned* Hb   = Ha + 16l * WI;                     // 16*WI (image)
    unsigned* mp   = Hb + 16l * WI;                     // 16*WI (image)
    float*    Cst  = (float*)(mp + 16l * WI);           // S fp32 linear
    unsigned short* Wp5i = (unsigned short*)(Cst + S);  // 20 tiles * 10240 shorts
    unsigned short* Wgi  = Wp5i + 20 * 10240;           // 32 tiles
    unsigned short* Woi  = Wgi + 32 * 10240;            // 48 tiles
    float*    bg4  = (float*)(Woi + 48 * 10240);        // 512
    float*    bo4  = bg4 + 512;                         // 512
    unsigned short* VKM = (unsigned short*)(bo4 + 512); // 5S bf16 linear
    unsigned* Zimg = (unsigned*)(VKM + 5 * S);          // 16*WZ (image)
    unsigned* cnt  = Zimg + 16l * WZ;                   // 256 u32 barrier counters
    unsigned* Xp   = cnt + 256;                         // 16*XW full, or XW slot

    const bool havex =
        ((char*)(Xp + 16l * XW) - (char*)d_ws) <= (long)ws_size;

    hipMemsetAsync(Hb, 0, 16l * WI * 4, stream);
    hipMemsetAsync(mp, 0, 16l * WI * 4, stream);
    hipMemsetAsync(cnt, 0, 256 * 4, stream);
    hipMemcpyAsync(Cst, c0, S * sizeof(float), hipMemcpyDeviceToDevice, stream);

    setup_all<<<1600, dim3(256), 0, stream>>>(W5, W8, b8, Wp5i, Wgi, bg4, Woi, bo4);
    if (havex)
        pack_x<<<32768, dim3(256), 0, stream>>>(x, (uint4*)Xp);

    mega<<<GRID, dim3(256), 0, stream>>>(
        x, (const unsigned*)Wgi, bg4, (const unsigned*)Wp5i, b5,
        (const unsigned*)Woi, bo4,
        Xp, Ha, Hb, mp, Cst, VKM, Zimg, out, cnt, havex ? 1 : 0);
}

// Round 9
// 1348.892 us; speedup vs baseline: 7.8836x; 7.8836x over previous
//
#include <hip/hip_runtime.h>
#include <hip/hip_bf16.h>

#define BB 16
#define TT 16
#define CC 128
#define HW 1024             // 32*32
#define PIX (CC*HW)         // 131072
#define STOT ((long)BB*PIX) // 2M

// B-image geometry v2: tiles of 128 pixels x 32 k, KBLOCK-MAJOR, no pads.
// word(row, kw) = (kw>>2)*512 + phys(row,kb)*4 + (kw&3), phys = (row+16*kb)&127
#define BTW 4096            // u32 words per B tile
#define WI  131072          // u32 words per batch, K=128 image (8 p-tiles * 4 k-tiles)
#define WZ  262144          // u32 words per batch, K=256 image (ZHZM)
#define XW  2097152         // u32 words per timestep of Xp (16 batches * WI)

typedef short short8 __attribute__((ext_vector_type(8)));
typedef float f32x4  __attribute__((ext_vector_type(4)));

__device__ __forceinline__ float sigf(float x) { return 1.0f / (1.0f + __expf(-x)); }
__device__ __forceinline__ float tanhf_fast(float x) {
    float ax = fabsf(x);
    float t = __expf(-2.0f * ax);
    float r = (1.0f - t) / (1.0f + t);
    return copysignf(r, x);
}

// ---- packed hi/lo bf16: uint32 = (bf16(x)<<16) | bf16(x - bf16(x)) ----
__device__ __forceinline__ unsigned pack_hl(float x) {
    unsigned u = __float_as_uint(x);
    unsigned hi = (u + 0x7fffu + ((u >> 16) & 1u)) >> 16;
    float r = x - __uint_as_float(hi << 16);
    unsigned v = __float_as_uint(r);
    unsigned lo = (v + 0x7fffu + ((v >> 16) & 1u)) >> 16;
    return (hi << 16) | lo;
}
__device__ __forceinline__ float unpack_hl(unsigned p) {
    return __uint_as_float(p & 0xffff0000u) + __uint_as_float(p << 16);
}
__device__ __forceinline__ unsigned short pack_bf16(float x) {
    unsigned u = __float_as_uint(x);
    return (unsigned short)((u + 0x7fffu + ((u >> 16) & 1u)) >> 16);
}
__device__ __forceinline__ float bf16f(unsigned short s) {
    return __uint_as_float(((unsigned)s) << 16);
}

// B-side hi extraction only (2-pass scheme: B consumed as RNE bf16)
__device__ __forceinline__ short8 split_hi(uint4 a, uint4 b) {
    unsigned w[8] = {a.x, a.y, a.z, a.w, b.x, b.y, b.z, b.w};
    union U { unsigned u[4]; short8 s; } h;
    #pragma unroll
    for (int j = 0; j < 4; ++j)
        h.u[j] = (w[2*j] >> 16) | (w[2*j+1] & 0xffff0000u);
    return h.s;
}

// B tile addr v2 (u32 units): kblock-major + 16-row rotation per kblock
__device__ __forceinline__ int taddr2(int row, int kw) {
    int kb = kw >> 2;
    return (kb << 9) + (((row + (kb << 4)) & 127) << 2) + (kw & 3);
}
// word index of element (pixel p, k-channel c) in a per-batch image with nkt k-tiles
__device__ __forceinline__ long bwidx2(int p, int c, int nkt) {
    return ((long)((p >> 7) * nkt + (c >> 5)) << 12) + taddr2(p & 127, c & 31);
}

typedef __attribute__((address_space(3))) unsigned lds_u32_t;
typedef __attribute__((address_space(1))) const unsigned gbl_u32_t;
__device__ __forceinline__ void gld16(const void* g, unsigned* l) {
    __builtin_amdgcn_global_load_lds((gbl_u32_t*)g, (lds_u32_t*)l, 16, 0, 0);
}

// ---------------- MFMA GEMM with fused epilogues (2-pass: ahi*bhi + alo*bhi) ----------------
// MODE 1: bf16 store (+ scalar bias[row])        -> outv = ushort* (linear)
// MODE 2: LSTM fuse: rows c*4+gate; stv=Cst(f32 linear), outv=Ha image (packed)
// MODE 3: final fuse: rows c*4+gate(3+pad); stv=mp image, outv=Hb image, Hout opt fp32 linear
// B-source: m0>=m_split -> imgB(kofs 0); k0>=k_split -> imgB(kofs k_split); else imgA.
// Both imgA/imgB are kblock-major B-tile images (packed hi/lo u32), DMA-staged.
template<int MODE>
__global__ __launch_bounds__(256, 2) void gemm_mfma(
    const unsigned* __restrict__ Wp, const float* __restrict__ bias,
    const unsigned* __restrict__ imgA, long wA,
    const unsigned* __restrict__ imgB, long wB, int nktB,
    int k_split, int m_split,
    void* __restrict__ outv, void* __restrict__ stv, float* __restrict__ Hout,
    int M, int K)
{
    __shared__ __align__(16) unsigned As[5120];   // 20480 B weight tile image
    __shared__ __align__(16) unsigned Bs[4096];   // 16384 B activation tile image

    const int b  = blockIdx.z;
    const int n0 = blockIdx.x * 128;
    const int m0 = blockIdx.y * 128;
    const int t  = threadIdx.x;
    const int lane = t & 63;
    const int w  = t >> 6;
    const int wm = w & 1, wn = w >> 1;
    const int g  = lane >> 4, pl = lane & 15;
    const int cb = ((g + (pl >> 2)) & 3) << 4;    // A-plane 16B-block rotation

    f32x4 acc[4][4] = {};

    for (int k0 = 0; k0 < K; k0 += 32) {
        // stage A (weights): 5 DMA rounds
        {
            const char* gA = (const char*)Wp +
                (size_t)((m0 >> 7) * (K >> 5) + (k0 >> 5)) * 20480;
            #pragma unroll
            for (int r = 0; r < 5; ++r)
                gld16(gA + r * 4096 + t * 16, As + r * 1024 + t * 4);
        }
        // stage B (activation image): exactly 4 DMA rounds (16 KB tile)
        const bool useB = (m0 >= m_split) || (k0 >= k_split);
        {
            const int kc = useB ? (k0 - ((m0 >= m_split) ? 0 : k_split)) : k0;
            const unsigned* img = useB ? imgB : imgA;
            const long bw = useB ? wB : wA;
            const int nkt = useB ? nktB : 4;
            const char* gB = (const char*)(img + (long)b * bw +
                ((long)((n0 >> 7) * nkt + (kc >> 5)) << 12));
            #pragma unroll
            for (int r = 0; r < 4; ++r)
                gld16(gB + r * 4096 + t * 16, Bs + r * 1024 + t * 4);
        }
        __syncthreads();

        short8 ahi[4], alo[4], bhi[4];
        #pragma unroll
        for (int mt = 0; mt < 4; ++mt) {
            int row = 64 * wm + 16 * mt + pl;
            const char* pa = (const char*)As + row * 80 + cb;
            ahi[mt] = *(const short8*)pa;
            alo[mt] = *(const short8*)(pa + 10240);
        }
        #pragma unroll
        for (int nt = 0; nt < 4; ++nt) {
            int prow = 64 * wn + 16 * nt + pl;
            uint4 w0 = *(const uint4*)(Bs + taddr2(prow, 8 * g));
            uint4 w1 = *(const uint4*)(Bs + taddr2(prow, 8 * g + 4));
            bhi[nt] = split_hi(w0, w1);
        }
        #pragma unroll
        for (int mt = 0; mt < 4; ++mt)
            #pragma unroll
            for (int nt = 0; nt < 4; ++nt) {
                acc[mt][nt] = __builtin_amdgcn_mfma_f32_16x16x32_bf16(ahi[mt], bhi[nt], acc[mt][nt], 0, 0, 0);
                acc[mt][nt] = __builtin_amdgcn_mfma_f32_16x16x32_bf16(alo[mt], bhi[nt], acc[mt][nt], 0, 0, 0);
            }
        __syncthreads();
    }

    if (MODE == 1) {
        #pragma unroll
        for (int mt = 0; mt < 4; ++mt)
            #pragma unroll
            for (int r = 0; r < 4; ++r) {
                int row = m0 + 64 * wm + 16 * mt + 4 * g + r;
                float bb = bias[row];
                #pragma unroll
                for (int nt = 0; nt < 4; ++nt) {
                    int col = n0 + 64 * wn + 16 * nt + pl;
                    ((unsigned short*)outv)[((long)b * M + row) * HW + col] =
                        pack_bf16(acc[mt][nt][r] + bb);
                }
            }
    } else {
        // rows interleaved c*4+gate: one thread's f32x4 = all 4 gates of channel c
        const float4* bias4 = (const float4*)bias;
        unsigned* Hp = (unsigned*)outv;
        #pragma unroll
        for (int mt = 0; mt < 4; ++mt) {
            int c = (m0 >> 2) + 16 * wm + 4 * mt + g;
            float4 bb = bias4[c];
            #pragma unroll
            for (int nt = 0; nt < 4; ++nt) {
                int p = n0 + 64 * wn + 16 * nt + pl;
                long lidx = (long)b * PIX + (long)c * HW + p;       // linear (Cst, Hout)
                long widx = (long)b * WI + bwidx2(p, c, 4);         // image (Ha/Hb/mp)
                float v0 = acc[mt][nt][0] + bb.x;
                float v1 = acc[mt][nt][1] + bb.y;
                float v2 = acc[mt][nt][2] + bb.z;
                float v3 = acc[mt][nt][3] + bb.w;
                if (MODE == 2) {
                    float* Cst = (float*)stv;
                    float cc = Cst[lidx] * sigf(v0) + sigf(v1) * tanhf_fast(v2);
                    Cst[lidx] = cc;
                    Hp[widx] = pack_hl(sigf(v3) * tanhf_fast(cc));
                } else {
                    unsigned* mp = (unsigned*)stv;
                    float ot = sigf(v0), gt = tanhf_fast(v1), it = sigf(v2);
                    float mo = unpack_hl(mp[widx]);
                    float mn = gt * it + (1.0f - it) * mo;
                    mp[widx] = pack_hl(mn);
                    float hv = ot * mn;
                    Hp[widx] = pack_hl(hv);
                    if (Hout) Hout[lidx] = hv;
                }
            }
        }
    }
}

// ---------------- attention: VKM bf16 [16][640][1024] -> Zimg (kblock-major, lo=0) ----------------
// block = (b, c-quad): 4 channels per block, dense uint4 stores
__global__ __launch_bounds__(1024) void attn_kernel(
    const unsigned short* __restrict__ VKM, unsigned* __restrict__ Zimg)
{
    __shared__ float qs[4][32 * 33];
    const int tid = threadIdx.x;
    const int b = blockIdx.x >> 5, cq = blockIdx.x & 31;
    const int c0 = cq << 2;
    const long base = (long)b * 640 * HW;

    #pragma unroll
    for (int cc = 0; cc < 4; ++cc)
        qs[cc][(tid >> 5) * 33 + (tid & 31)] =
            bf16f(VKM[base + (long)(256 + c0 + cc) * HW + tid]);
    __syncthreads();

    const int i = tid >> 5, j = tid & 31;
    uint4 oh, om;
    unsigned* ohw = (unsigned*)&oh;
    unsigned* omw = (unsigned*)&om;
    #pragma unroll
    for (int cc = 0; cc < 4; ++cc) {
        const long cbs = base + (long)(c0 + cc) * HW;
        float qhT = qs[cc][j * 33 + i];
        float vh  = bf16f(VKM[cbs + tid]);
        float kh  = bf16f(VKM[cbs + 128l * HW + tid]);
        float km  = bf16f(VKM[cbs + 384l * HW + tid]);
        float vm  = bf16f(VKM[cbs + 512l * HW + tid]);

        float sh = kh * qhT, sm = qhT * km;
        float mh = sh, mm = sm;
        #pragma unroll
        for (int o = 16; o > 0; o >>= 1) {
            mh = fmaxf(mh, __shfl_xor(mh, o, 32));
            mm = fmaxf(mm, __shfl_xor(mm, o, 32));
        }
        float eh = __expf(sh - mh), em = __expf(sm - mm);
        float s1 = eh, s2 = em;
        #pragma unroll
        for (int o = 16; o > 0; o >>= 1) {
            s1 += __shfl_xor(s1, o, 32);
            s2 += __shfl_xor(s2, o, 32);
        }
        ohw[cc] = ((unsigned)pack_bf16(vh * (eh / s1))) << 16;
        omw[cc] = ((unsigned)pack_bf16(vm * (em / s2))) << 16;
    }
    const int kt = c0 >> 5, kb = (c0 & 31) >> 2;
    const int phys = ((tid & 127) + (kb << 4)) & 127;
    long u4 = ((long)b << 16) + ((long)(tid >> 7) << 13) + (kb << 7) + phys;
    ((uint4*)Zimg)[u4 + ((long)kt << 10)]       = oh;   // zh at k=c0..c0+3
    ((uint4*)Zimg)[u4 + ((long)(kt + 4) << 10)] = om;   // zm at k=c0+128..
}

// ---------------- pack x into B-image format: dest-linear streaming (R6-proven) ----------------
// one uint4 per thread; dest index == idx (one-shot) — fully coalesced both sides
// x layout is [B][T][C][HW] (batch-major)
__global__ __launch_bounds__(256) void pack_x(
    const float* __restrict__ x, uint4* __restrict__ Xp, int tstart, int oneshot)
{
    long idx = (long)blockIdx.x * 256 + threadIdx.x;
    int t = tstart + (int)(idx >> 19);
    long rest = idx & ((1l << 19) - 1);
    int b = (int)(rest >> 15);
    int v = (int)(rest & 32767);            // ptile*4096 + kt*1024 + kb*128 + phys
    int kb = (v >> 7) & 7, phys = v & 127;
    int row = (phys - (kb << 4)) & 127;
    int p = ((v >> 12) << 7) + row;
    int c = (((v >> 10) & 3) << 5) + (kb << 2);
    const float* xs = x + (((long)b * TT + t) * CC + c) * HW + p;
    uint4 o;
    o.x = pack_hl(xs[0]);
    o.y = pack_hl(xs[HW]);
    o.z = pack_hl(xs[2 * HW]);
    o.w = pack_hl(xs[3 * HW]);
    Xp[oneshot ? idx : rest] = o;
}

// ---------------- one-shot setup: build pre-swizzled hi/lo weight tile images ----------------
__device__ __forceinline__ void wimg(unsigned short* img, int Ktiles, int r, int k, float v) {
    int tile = (r >> 7) * Ktiles + (k >> 5);
    int row = r & 127, ks = k & 31;
    unsigned short* p = img + (size_t)tile * 10240;   // 10240 shorts = 20480 B per tile
    int off = row * 40 + ((((ks >> 3) + (row >> 2)) & 3) << 3) + (ks & 7);
    unsigned u = __float_as_uint(v);
    unsigned short hi = (unsigned short)((u + 0x7fffu + ((u >> 16) & 1u)) >> 16);
    float rr = v - __uint_as_float((unsigned)hi << 16);
    unsigned u2 = __float_as_uint(rr);
    unsigned short lo = (unsigned short)((u2 + 0x7fffu + ((u2 >> 16) & 1u)) >> 16);
    p[off] = hi;
    p[off + 5120] = lo;                               // lo plane at +10240 B
}

__global__ __launch_bounds__(256) void setup_all(
    const float* __restrict__ W5, const float* __restrict__ W8, const float* __restrict__ b8,
    unsigned short* __restrict__ Wp5i,
    unsigned short* __restrict__ Wgi, float* __restrict__ bg4,
    unsigned short* __restrict__ Woi, float* __restrict__ bo4)
{
    int idx = blockIdx.x * 256 + threadIdx.x;
    if (idx < 81920) {                       // W5 [640][128] -> Wp5 image (Ktiles=4)
        int r = idx >> 7, k = idx & 127;
        wimg(Wp5i, 4, r, k, W5[idx]);
        return;
    }
    idx -= 81920;
    if (idx < 131072) {                      // Wg: rows c*4+gate, convs 10..13, K=256 (Ktiles=8)
        int rr = idx >> 8, k = idx & 255;
        int c = rr >> 2, gg = rr & 3;
        wimg(Wgi, 8, rr, k, W8[((long)(4 + gg) * 128 + c) * 256 + k]);
        if (k == 0) bg4[rr] = b8[(4 + gg) * 128 + c];
        return;
    }
    idx -= 131072;                           // Wo: 512 rows x 384, conv6 folded (Ktiles=12)
    if (idx >= 512 * 384) return;
    int rr = idx / 384, k = idx - rr * 384;
    int c = rr >> 2, gg = rr & 3;
    float wv = 0.0f;
    if (gg < 3) {
        const float* wr = W8 + ((long)(1 + gg) * 128 + c) * 256;
        if (k < 128) {
            wv = wr[k];
        } else {
            int i = k - 128;
            float s = 0.0f;
            for (int j = 0; j < 128; ++j)
                s += wr[128 + j] * W8[(long)j * 256 + i];   // Wz = W8[0]
            wv = s;
        }
    }
    wimg(Woi, 12, rr, k, wv);
    if (k == 0) {
        float bb = 0.0f;
        if (gg < 3) {
            bb = b8[(1 + gg) * 128 + c];
            const float* wr = W8 + ((long)(1 + gg) * 128 + c) * 256;
            for (int j = 0; j < 128; ++j) bb += wr[128 + j] * b8[j];  // bz = b8[0]
        }
        bo4[rr] = bb;
    }
}

extern "C" void kernel_launch(void* const* d_in, const int* in_sizes, int n_in,
                              void* d_out, int out_size, void* d_ws, size_t ws_size,
                              hipStream_t stream)
{
    const float* x  = (const float*)d_in[0];   // [16][16][128][1024]  (B-major)
    const float* c0 = (const float*)d_in[1];
    const float* W5 = (const float*)d_in[2];   // [640][128]
    const float* b5 = (const float*)d_in[3];   // [640]
    const float* W8 = (const float*)d_in[4];   // [8][128][256]
    const float* b8 = (const float*)d_in[5];   // [8][128]
    float* out = (float*)d_out;

    const long S = STOT;
    unsigned* Ha   = (unsigned*)d_ws;                   // 16*WI (image)
    unsigned* Hb   = Ha + 16l * WI;                     // 16*WI (image)
    unsigned* mp   = Hb + 16l * WI;                     // 16*WI (image)
    float*    Cst  = (float*)(mp + 16l * WI);           // S fp32 linear
    unsigned short* Wp5i = (unsigned short*)(Cst + S);  // 20 tiles * 10240 shorts
    unsigned short* Wgi  = Wp5i + 20 * 10240;           // 32 tiles
    unsigned short* Woi  = Wgi + 32 * 10240;            // 48 tiles
    float*    bg4  = (float*)(Woi + 48 * 10240);        // 512
    float*    bo4  = bg4 + 512;                         // 512
    unsigned short* VKM = (unsigned short*)(bo4 + 512); // 5S bf16 linear
    unsigned* Zimg = (unsigned*)(VKM + 5 * S);          // 16*WZ (image)
    unsigned* Xp   = Zimg + 16l * WZ;                   // 16*XW full, or XW slot

    const bool havex =
        ((char*)(Xp + 16l * XW) - (char*)d_ws) <= (long)ws_size;

    hipMemsetAsync(Hb, 0, 16l * WI * 4, stream);
    hipMemsetAsync(mp, 0, 16l * WI * 4, stream);
    hipMemcpyAsync(Cst, c0, S * sizeof(float), hipMemcpyDeviceToDevice, stream);

    setup_all<<<1600, dim3(256), 0, stream>>>(W5, W8, b8, Wp5i, Wgi, bg4, Woi, bo4);
    if (havex)
        pack_x<<<32768, dim3(256), 0, stream>>>(x, (uint4*)Xp, 0, 1);

    const int BIG = 1 << 30;
    const dim3 blk(256);
    for (int t = 0; t < TT; ++t) {
        if (!havex)
            pack_x<<<2048, dim3(256), 0, stream>>>(x, (uint4*)Xp, t, 0);
        const unsigned* Xpt = Xp + (havex ? (long)t * XW : 0l);

        // gates = Wg * [Hb ; x_t], fused LSTM -> Cst, Ha image  (M=512, K=256)
        gemm_mfma<2><<<dim3(8, 4, 16), blk, 0, stream>>>(
            (const unsigned*)Wgi, bg4, Hb, (long)WI, Xpt, (long)WI, 4,
            128, BIG, Ha, Cst, nullptr, 512, 256);

        // vh,kh,qh (Ha) + km,vm (mp)   (M=640, K=128) -> VKM bf16 linear
        gemm_mfma<1><<<dim3(8, 5, 16), blk, 0, stream>>>(
            (const unsigned*)Wp5i, b5, Ha, (long)WI, mp, (long)WI, 4,
            BIG, 384, VKM, nullptr, nullptr, 640, 128);

        attn_kernel<<<512, dim3(1024), 0, stream>>>(VKM, Zimg);

        // o,g,i = Wo * [Ha ; Zimg] (conv6 folded), fused final -> mp, Hb (+out)
        gemm_mfma<3><<<dim3(8, 4, 16), blk, 0, stream>>>(
            (const unsigned*)Woi, bo4, Ha, (long)WI, Zimg, (long)WZ, 8,
            128, BIG, Hb, mp, (t == TT - 1) ? out : nullptr, 512, 384);
    }
}

// Round 10
// 1262.955 us; speedup vs baseline: 8.4200x; 1.0680x over previous
//
#include <hip/hip_runtime.h>
#include <hip/hip_bf16.h>

#define BB 16
#define TT 16
#define CC 128
#define HW 1024             // 32*32
#define PIX (CC*HW)         // 131072
#define STOT ((long)BB*PIX) // 2M

// B-image geometry v3: tiles of 128 pixels x 32 k, u16 (bf16), kblock-major (8 ch),
// a16(row,k) = (k>>3)*1024 + phys*8 + (k&7), phys = (row + 16*(k>>3)) & 127
#define TW16 4096           // u16 per B tile (8192 B)
#define WI16 131072         // u16 per batch, K=128 image (8 ptiles * 4 ktiles)
#define WZ16 262144         // u16 per batch, K=256 image (ZHZM)
#define XW16 2097152        // u16 per timestep of Xp (16 batches * WI16)

typedef short short8 __attribute__((ext_vector_type(8)));
typedef float f32x4  __attribute__((ext_vector_type(4)));

__device__ __forceinline__ float sigf(float x) { return 1.0f / (1.0f + __expf(-x)); }
__device__ __forceinline__ float tanhf_fast(float x) {
    float ax = fabsf(x);
    float t = __expf(-2.0f * ax);
    float r = (1.0f - t) / (1.0f + t);
    return copysignf(r, x);
}

__device__ __forceinline__ unsigned short pack_bf16(float x) {
    unsigned u = __float_as_uint(x);
    return (unsigned short)((u + 0x7fffu + ((u >> 16) & 1u)) >> 16);
}
__device__ __forceinline__ float bf16f(unsigned short s) {
    return __uint_as_float(((unsigned)s) << 16);
}

// u16 index of element (pixel p, k-channel c) in a per-batch v3 image with nkt k-tiles
__device__ __forceinline__ long bidx16(int p, int c, int nkt) {
    int kb = (c >> 3) & 3;
    int phys = ((p & 127) + (kb << 4)) & 127;
    return ((long)((p >> 7) * nkt + (c >> 5)) << 12) + (kb << 10) + (phys << 3) + (c & 7);
}

typedef __attribute__((address_space(3))) unsigned lds_u32_t;
typedef __attribute__((address_space(1))) const unsigned gbl_u32_t;
__device__ __forceinline__ void gld16(const void* g, unsigned* l) {
    __builtin_amdgcn_global_load_lds((gbl_u32_t*)g, (lds_u32_t*)l, 16, 0, 0);
}

// ---------------- MFMA GEMM, fused epilogues; 2-pass (ahi*b + alo*b), B pure bf16 ----------------
// MODE 1: bf16 store (+ scalar bias[row])  -> outv = ushort* (linear)
// MODE 2: LSTM fuse: stv=Cst(f32 linear), outv=Ha image (u16)
// MODE 3: final fuse: stv=mpf(f32 linear), simg=mp image(u16), outv=Hb image(u16), Hout opt
// B-source: m0>=m_split -> imgB(kofs 0); k0>=k_split -> imgB(kofs k_split); else imgA.
template<int MODE>
__global__ __launch_bounds__(256, 2) void gemm_mfma(
    const unsigned* __restrict__ Wp, const float* __restrict__ bias,
    const unsigned short* __restrict__ imgA, long wA,
    const unsigned short* __restrict__ imgB, long wB, int nktB,
    int k_split, int m_split,
    void* __restrict__ outv, void* __restrict__ stv,
    unsigned short* __restrict__ simg, float* __restrict__ Hout,
    int M, int K)
{
    __shared__ __align__(16) unsigned As[5120];   // 20480 B weight tile (hi/lo planes)
    __shared__ __align__(16) unsigned Bs[2048];   // 8192 B activation tile (bf16)

    const int b  = blockIdx.z;
    const int n0 = blockIdx.x * 128;
    const int m0 = blockIdx.y * 128;
    const int t  = threadIdx.x;
    const int lane = t & 63;
    const int w  = t >> 6;
    const int wm = w & 1, wn = w >> 1;
    const int g  = lane >> 4, pl = lane & 15;
    const int cb = ((g + (pl >> 2)) & 3) << 4;    // A-plane 16B-block rotation

    f32x4 acc[4][4] = {};

    for (int k0 = 0; k0 < K; k0 += 32) {
        // stage A (weights): 5 DMA rounds
        {
            const char* gA = (const char*)Wp +
                (size_t)((m0 >> 7) * (K >> 5) + (k0 >> 5)) * 20480;
            #pragma unroll
            for (int r = 0; r < 5; ++r)
                gld16(gA + r * 4096 + t * 16, As + r * 1024 + t * 4);
        }
        // stage B (bf16 image): 2 DMA rounds (8 KB tile)
        const bool useB = (m0 >= m_split) || (k0 >= k_split);
        {
            const int kc = useB ? (k0 - ((m0 >= m_split) ? 0 : k_split)) : k0;
            const unsigned short* img = useB ? imgB : imgA;
            const long bw = useB ? wB : wA;
            const int nkt = useB ? nktB : 4;
            const char* gB = (const char*)(img + (long)b * bw +
                ((long)((n0 >> 7) * nkt + (kc >> 5)) << 12));
            gld16(gB + t * 16, Bs + t * 4);
            gld16(gB + 4096 + t * 16, Bs + 1024 + t * 4);
        }
        __syncthreads();

        short8 ahi[4], alo[4], bfr[4];
        #pragma unroll
        for (int mt = 0; mt < 4; ++mt) {
            int row = 64 * wm + 16 * mt + pl;
            const char* pa = (const char*)As + row * 80 + cb;
            ahi[mt] = *(const short8*)pa;
            alo[mt] = *(const short8*)(pa + 10240);
        }
        #pragma unroll
        for (int nt = 0; nt < 4; ++nt) {
            int prow = 64 * wn + 16 * nt + pl;
            int phys = (prow + (g << 4)) & 127;
            bfr[nt] = *(const short8*)((const char*)Bs + g * 2048 + phys * 16);
        }
        #pragma unroll
        for (int mt = 0; mt < 4; ++mt)
            #pragma unroll
            for (int nt = 0; nt < 4; ++nt) {
                acc[mt][nt] = __builtin_amdgcn_mfma_f32_16x16x32_bf16(ahi[mt], bfr[nt], acc[mt][nt], 0, 0, 0);
                acc[mt][nt] = __builtin_amdgcn_mfma_f32_16x16x32_bf16(alo[mt], bfr[nt], acc[mt][nt], 0, 0, 0);
            }
        __syncthreads();
    }

    if (MODE == 1) {
        #pragma unroll
        for (int mt = 0; mt < 4; ++mt)
            #pragma unroll
            for (int r = 0; r < 4; ++r) {
                int row = m0 + 64 * wm + 16 * mt + 4 * g + r;
                float bb = bias[row];
                #pragma unroll
                for (int nt = 0; nt < 4; ++nt) {
                    int col = n0 + 64 * wn + 16 * nt + pl;
                    ((unsigned short*)outv)[((long)b * M + row) * HW + col] =
                        pack_bf16(acc[mt][nt][r] + bb);
                }
            }
    } else {
        // rows interleaved c*4+gate: one thread's f32x4 = all 4 gates of channel c
        const float4* bias4 = (const float4*)bias;
        unsigned short* Hp = (unsigned short*)outv;
        #pragma unroll
        for (int mt = 0; mt < 4; ++mt) {
            int c = (m0 >> 2) + 16 * wm + 4 * mt + g;
            float4 bb = bias4[c];
            #pragma unroll
            for (int nt = 0; nt < 4; ++nt) {
                int p = n0 + 64 * wn + 16 * nt + pl;
                long lidx = (long)b * PIX + (long)c * HW + p;       // linear (f32 state)
                long widx = (long)b * WI16 + bidx16(p, c, 4);       // u16 image
                float v0 = acc[mt][nt][0] + bb.x;
                float v1 = acc[mt][nt][1] + bb.y;
                float v2 = acc[mt][nt][2] + bb.z;
                float v3 = acc[mt][nt][3] + bb.w;
                if (MODE == 2) {
                    float* Cst = (float*)stv;
                    float cc = Cst[lidx] * sigf(v0) + sigf(v1) * tanhf_fast(v2);
                    Cst[lidx] = cc;
                    Hp[widx] = pack_bf16(sigf(v3) * tanhf_fast(cc));
                } else {
                    float* mpf = (float*)stv;
                    float ot = sigf(v0), gt = tanhf_fast(v1), it = sigf(v2);
                    float mo = mpf[lidx];
                    float mn = gt * it + (1.0f - it) * mo;
                    mpf[lidx] = mn;
                    simg[widx] = pack_bf16(mn);
                    float hv = ot * mn;
                    Hp[widx] = pack_bf16(hv);
                    if (Hout) Hout[lidx] = hv;
                }
            }
        }
    }
}

// ---------------- attention: VKM bf16 [16][640][1024] -> Zimg v3 (u16 bf16) ----------------
// block = (b, c-quad): 4 channels per block, dense uint2 stores
__global__ __launch_bounds__(1024) void attn_kernel(
    const unsigned short* __restrict__ VKM, unsigned short* __restrict__ Zimg)
{
    __shared__ float qs[4][32 * 33];
    const int tid = threadIdx.x;
    const int b = blockIdx.x >> 5, cq = blockIdx.x & 31;
    const int c0 = cq << 2;
    const long base = (long)b * 640 * HW;

    #pragma unroll
    for (int cc = 0; cc < 4; ++cc)
        qs[cc][(tid >> 5) * 33 + (tid & 31)] =
            bf16f(VKM[base + (long)(256 + c0 + cc) * HW + tid]);
    __syncthreads();

    const int i = tid >> 5, j = tid & 31;
    unsigned short zh[4], zm[4];
    #pragma unroll
    for (int cc = 0; cc < 4; ++cc) {
        const long cbs = base + (long)(c0 + cc) * HW;
        float qhT = qs[cc][j * 33 + i];
        float vh  = bf16f(VKM[cbs + tid]);
        float kh  = bf16f(VKM[cbs + 128l * HW + tid]);
        float km  = bf16f(VKM[cbs + 384l * HW + tid]);
        float vm  = bf16f(VKM[cbs + 512l * HW + tid]);

        float sh = kh * qhT, sm = qhT * km;
        float mh = sh, mm = sm;
        #pragma unroll
        for (int o = 16; o > 0; o >>= 1) {
            mh = fmaxf(mh, __shfl_xor(mh, o, 32));
            mm = fmaxf(mm, __shfl_xor(mm, o, 32));
        }
        float eh = __expf(sh - mh), em = __expf(sm - mm);
        float s1 = eh, s2 = em;
        #pragma unroll
        for (int o = 16; o > 0; o >>= 1) {
            s1 += __shfl_xor(s1, o, 32);
            s2 += __shfl_xor(s2, o, 32);
        }
        zh[cc] = pack_bf16(vh * (eh / s1));
        zm[cc] = pack_bf16(vm * (em / s2));
    }
    // zh at k=c0..c0+3 (ktile c0>>5), zm at k=c0+128 (ktile +4); 4 u16 = one uint2
    const int kt = c0 >> 5, kb = (c0 >> 3) & 3, sl = c0 & 7;
    const int phys = ((tid & 127) + (kb << 4)) & 127;
    long e16 = (long)b * WZ16 + ((long)((tid >> 7) * 8 + kt) << 12) +
               (kb << 10) + (phys << 3) + sl;
    uint2 oh, om;
    oh.x = (unsigned)zh[0] | ((unsigned)zh[1] << 16);
    oh.y = (unsigned)zh[2] | ((unsigned)zh[3] << 16);
    om.x = (unsigned)zm[0] | ((unsigned)zm[1] << 16);
    om.y = (unsigned)zm[2] | ((unsigned)zm[3] << 16);
    *(uint2*)(Zimg + e16)              = oh;
    *(uint2*)(Zimg + e16 + (4l << 12)) = om;
}

// ---------------- pack x into v3 bf16 image: dest-linear streaming ----------------
// one thread = one uint4 = 8 u16 = one row's 8 channels of one kblock.
// x layout is [B][T][C][HW] (batch-major)
__global__ __launch_bounds__(256) void pack_x(
    const float* __restrict__ x, uint4* __restrict__ Xp, int tstart, int oneshot)
{
    long q = (long)blockIdx.x * 256 + threadIdx.x;
    long e = q << 3;                        // u16 index
    int t = tstart + (int)(e >> 21);
    long r = e & ((1l << 21) - 1);
    int b = (int)(r >> 17);
    int v = (int)(r & ((1 << 17) - 1));     // u16 within batch image
    int tile = v >> 12;                     // ptile*4 + ktile
    int pt = tile >> 2, kt = tile & 3;
    int ww = v & 4095;
    int kb = ww >> 10, phys = (ww >> 3) & 127;
    int row = (phys - (kb << 4)) & 127;
    int p = (pt << 7) + row;
    int c = (kt << 5) + (kb << 3);
    const float* xs = x + (((long)b * TT + t) * CC + c) * HW + p;
    union { unsigned short s[8]; uint4 u; } o;
    #pragma unroll
    for (int jj = 0; jj < 8; ++jj)
        o.s[jj] = pack_bf16(xs[(long)jj * HW]);
    Xp[oneshot ? q : (q & ((1l << 18) - 1))] = o.u;
}

// ---------------- one-shot setup: build pre-swizzled hi/lo weight tile images ----------------
__device__ __forceinline__ void wimg(unsigned short* img, int Ktiles, int r, int k, float v) {
    int tile = (r >> 7) * Ktiles + (k >> 5);
    int row = r & 127, ks = k & 31;
    unsigned short* p = img + (size_t)tile * 10240;   // 10240 shorts = 20480 B per tile
    int off = row * 40 + ((((ks >> 3) + (row >> 2)) & 3) << 3) + (ks & 7);
    unsigned u = __float_as_uint(v);
    unsigned short hi = (unsigned short)((u + 0x7fffu + ((u >> 16) & 1u)) >> 16);
    float rr = v - __uint_as_float((unsigned)hi << 16);
    unsigned u2 = __float_as_uint(rr);
    unsigned short lo = (unsigned short)((u2 + 0x7fffu + ((u2 >> 16) & 1u)) >> 16);
    p[off] = hi;
    p[off + 5120] = lo;                               // lo plane at +10240 B
}

__global__ __launch_bounds__(256) void setup_all(
    const float* __restrict__ W5, const float* __restrict__ W8, const float* __restrict__ b8,
    unsigned short* __restrict__ Wp5i,
    unsigned short* __restrict__ Wgi, float* __restrict__ bg4,
    unsigned short* __restrict__ Woi, float* __restrict__ bo4)
{
    int idx = blockIdx.x * 256 + threadIdx.x;
    if (idx < 81920) {                       // W5 [640][128] -> Wp5 image (Ktiles=4)
        int r = idx >> 7, k = idx & 127;
        wimg(Wp5i, 4, r, k, W5[idx]);
        return;
    }
    idx -= 81920;
    if (idx < 131072) {                      // Wg: rows c*4+gate, convs 10..13, K=256 (Ktiles=8)
        int rr = idx >> 8, k = idx & 255;
        int c = rr >> 2, gg = rr & 3;
        wimg(Wgi, 8, rr, k, W8[((long)(4 + gg) * 128 + c) * 256 + k]);
        if (k == 0) bg4[rr] = b8[(4 + gg) * 128 + c];
        return;
    }
    idx -= 131072;                           // Wo: 512 rows x 384, conv6 folded (Ktiles=12)
    if (idx >= 512 * 384) return;
    int rr = idx / 384, k = idx - rr * 384;
    int c = rr >> 2, gg = rr & 3;
    float wv = 0.0f;
    if (gg < 3) {
        const float* wr = W8 + ((long)(1 + gg) * 128 + c) * 256;
        if (k < 128) {
            wv = wr[k];
        } else {
            int i = k - 128;
            float s = 0.0f;
            for (int j = 0; j < 128; ++j)
                s += wr[128 + j] * W8[(long)j * 256 + i];   // Wz = W8[0]
            wv = s;
        }
    }
    wimg(Woi, 12, rr, k, wv);
    if (k == 0) {
        float bb = 0.0f;
        if (gg < 3) {
            bb = b8[(1 + gg) * 128 + c];
            const float* wr = W8 + ((long)(1 + gg) * 128 + c) * 256;
            for (int j = 0; j < 128; ++j) bb += wr[128 + j] * b8[j];  // bz = b8[0]
        }
        bo4[rr] = bb;
    }
}

extern "C" void kernel_launch(void* const* d_in, const int* in_sizes, int n_in,
                              void* d_out, int out_size, void* d_ws, size_t ws_size,
                              hipStream_t stream)
{
    const float* x  = (const float*)d_in[0];   // [16][16][128][1024]  (B-major)
    const float* c0 = (const float*)d_in[1];
    const float* W5 = (const float*)d_in[2];   // [640][128]
    const float* b5 = (const float*)d_in[3];   // [640]
    const float* W8 = (const float*)d_in[4];   // [8][128][256]
    const float* b8 = (const float*)d_in[5];   // [8][128]
    float* out = (float*)d_out;

    const long S = STOT;
    unsigned short* Ha  = (unsigned short*)d_ws;        // 16*WI16 u16 image
    unsigned short* Hb  = Ha + 16l * WI16;              // 16*WI16
    unsigned short* mpi = Hb + 16l * WI16;              // 16*WI16 (mp bf16 image)
    float* mpf = (float*)(mpi + 16l * WI16);            // S fp32 (mp full state)
    float* Cst = mpf + S;                               // S fp32
    unsigned short* Wp5i = (unsigned short*)(Cst + S);  // 20 tiles * 10240 shorts
    unsigned short* Wgi  = Wp5i + 20 * 10240;           // 32 tiles
    unsigned short* Woi  = Wgi + 32 * 10240;            // 48 tiles
    float* bg4 = (float*)(Woi + 48 * 10240);            // 512
    float* bo4 = bg4 + 512;                             // 512
    unsigned short* VKM  = (unsigned short*)(bo4 + 512);   // 5S bf16 linear
    unsigned short* Zimg = VKM + 5 * S;                    // 16*WZ16 u16 image
    unsigned short* Xp   = Zimg + 16l * WZ16;              // 16*XW16 full, or XW16 slot

    const bool havex =
        ((char*)(Xp + 16l * XW16) - (char*)d_ws) <= (long)ws_size;

    hipMemsetAsync(Hb,  0, 16l * WI16 * 2, stream);
    hipMemsetAsync(mpi, 0, 16l * WI16 * 2, stream);
    hipMemsetAsync(mpf, 0, S * sizeof(float), stream);
    hipMemcpyAsync(Cst, c0, S * sizeof(float), hipMemcpyDeviceToDevice, stream);

    setup_all<<<1600, dim3(256), 0, stream>>>(W5, W8, b8, Wp5i, Wgi, bg4, Woi, bo4);
    if (havex)
        pack_x<<<16384, dim3(256), 0, stream>>>(x, (uint4*)Xp, 0, 1);

    const int BIG = 1 << 30;
    const dim3 blk(256);
    for (int t = 0; t < TT; ++t) {
        if (!havex)
            pack_x<<<1024, dim3(256), 0, stream>>>(x, (uint4*)Xp, t, 0);
        const unsigned short* Xpt = Xp + (havex ? (long)t * XW16 : 0l);

        // gates = Wg * [Hb ; x_t], fused LSTM -> Cst, Ha image  (M=512, K=256)
        gemm_mfma<2><<<dim3(8, 4, 16), blk, 0, stream>>>(
            (const unsigned*)Wgi, bg4, Hb, (long)WI16, Xpt, (long)WI16, 4,
            128, BIG, Ha, Cst, nullptr, nullptr, 512, 256);

        // vh,kh,qh (Ha) + km,vm (mpi)   (M=640, K=128) -> VKM bf16 linear
        gemm_mfma<1><<<dim3(8, 5, 16), blk, 0, stream>>>(
            (const unsigned*)Wp5i, b5, Ha, (long)WI16, mpi, (long)WI16, 4,
            BIG, 384, VKM, nullptr, nullptr, nullptr, 640, 128);

        attn_kernel<<<512, dim3(1024), 0, stream>>>(VKM, Zimg);

        // o,g,i = Wo * [Ha ; Zimg] (conv6 folded), fused final -> mpf/mpi, Hb (+out)
        gemm_mfma<3><<<dim3(8, 4, 16), blk, 0, stream>>>(
            (const unsigned*)Woi, bo4, Ha, (long)WI16, Zimg, (long)WZ16, 8,
            128, BIG, Hb, mpf, mpi, (t == TT - 1) ? out : nullptr, 512, 384);
    }
}

// Round 11
// 1122.192 us; speedup vs baseline: 9.4762x; 1.1254x over previous
//
#include <hip/hip_runtime.h>
#include <hip/hip_bf16.h>

#define BB 16
#define TT 16
#define CC 128
#define HW 1024             // 32*32
#define PIX (CC*HW)         // 131072
#define STOT ((long)BB*PIX) // 2M

// image geometry v3 (A and B): tiles of 128 rows x 32 k, u16 bf16, kblock-major (8 ch),
// a16(row,k) = (k>>3)*1024 + phys*8 + (k&7), phys = (row + 16*(k>>3)) & 127
#define TW16 4096           // u16 per tile (8192 B)
#define WI16 131072         // u16 per batch, K=128 image (8 ptiles * 4 ktiles)
#define WZ16 262144         // u16 per batch, K=256 image (ZHZM)
#define XW16 2097152        // u16 per timestep of Xp (16 batches * WI16)

typedef short short8 __attribute__((ext_vector_type(8)));
typedef float f32x4  __attribute__((ext_vector_type(4)));

__device__ __forceinline__ float sigf(float x) { return 1.0f / (1.0f + __expf(-x)); }
__device__ __forceinline__ float tanhf_fast(float x) {
    float ax = fabsf(x);
    float t = __expf(-2.0f * ax);
    float r = (1.0f - t) / (1.0f + t);
    return copysignf(r, x);
}

__device__ __forceinline__ unsigned short pack_bf16(float x) {
    unsigned u = __float_as_uint(x);
    return (unsigned short)((u + 0x7fffu + ((u >> 16) & 1u)) >> 16);
}
__device__ __forceinline__ float bf16f(unsigned short s) {
    return __uint_as_float(((unsigned)s) << 16);
}

// u16 index of element (pixel p, k-channel c) in a per-batch v3 image with nkt k-tiles
__device__ __forceinline__ long bidx16(int p, int c, int nkt) {
    int kb = (c >> 3) & 3;
    int phys = ((p & 127) + (kb << 4)) & 127;
    return ((long)((p >> 7) * nkt + (c >> 5)) << 12) + (kb << 10) + (phys << 3) + (c & 7);
}

typedef __attribute__((address_space(3))) unsigned lds_u32_t;
typedef __attribute__((address_space(1))) const unsigned gbl_u32_t;
__device__ __forceinline__ void gld16(const void* g, unsigned* l) {
    __builtin_amdgcn_global_load_lds((gbl_u32_t*)g, (lds_u32_t*)l, 16, 0, 0);
}

// ---------------- MFMA GEMM, fused epilogues; 1-pass, A and B pure bf16 v3 images ----------------
// MODE 1: bf16 store (+ scalar bias[row])  -> outv = ushort* (linear)
// MODE 2: LSTM fuse: stv=Cst(f32 linear), outv=Ha image (u16)
// MODE 3: final fuse: stv=mpf(f32 linear), simg=mp image(u16), outv=Hb image(u16), Hout opt
// B-source: m0>=m_split -> imgB(kofs 0); k0>=k_split -> imgB(kofs k_split); else imgA.
template<int MODE>
__global__ __launch_bounds__(256, 2) void gemm_mfma(
    const unsigned short* __restrict__ Wp, const float* __restrict__ bias,
    const unsigned short* __restrict__ imgA, long wA,
    const unsigned short* __restrict__ imgB, long wB, int nktB,
    int k_split, int m_split,
    void* __restrict__ outv, void* __restrict__ stv,
    unsigned short* __restrict__ simg, float* __restrict__ Hout,
    int M, int K)
{
    __shared__ __align__(16) unsigned As[2048];   // 8192 B weight tile (bf16 v3)
    __shared__ __align__(16) unsigned Bs[2048];   // 8192 B activation tile (bf16 v3)

    const int b  = blockIdx.z;
    const int n0 = blockIdx.x * 128;
    const int m0 = blockIdx.y * 128;
    const int t  = threadIdx.x;
    const int lane = t & 63;
    const int w  = t >> 6;
    const int wm = w & 1, wn = w >> 1;
    const int g  = lane >> 4, pl = lane & 15;

    f32x4 acc[4][4] = {};

    for (int k0 = 0; k0 < K; k0 += 32) {
        // stage A (weights): 2 DMA rounds
        {
            const char* gA = (const char*)(Wp +
                (size_t)((m0 >> 7) * (K >> 5) + (k0 >> 5)) * TW16);
            gld16(gA + t * 16, As + t * 4);
            gld16(gA + 4096 + t * 16, As + 1024 + t * 4);
        }
        // stage B (activations): 2 DMA rounds
        const bool useB = (m0 >= m_split) || (k0 >= k_split);
        {
            const int kc = useB ? (k0 - ((m0 >= m_split) ? 0 : k_split)) : k0;
            const unsigned short* img = useB ? imgB : imgA;
            const long bw = useB ? wB : wA;
            const int nkt = useB ? nktB : 4;
            const char* gB = (const char*)(img + (long)b * bw +
                ((long)((n0 >> 7) * nkt + (kc >> 5)) << 12));
            gld16(gB + t * 16, Bs + t * 4);
            gld16(gB + 4096 + t * 16, Bs + 1024 + t * 4);
        }
        __syncthreads();

        short8 afr[4], bfr[4];
        #pragma unroll
        for (int mt = 0; mt < 4; ++mt) {
            int row = 64 * wm + 16 * mt + pl;
            int phys = (row + (g << 4)) & 127;
            afr[mt] = *(const short8*)((const char*)As + g * 2048 + phys * 16);
        }
        #pragma unroll
        for (int nt = 0; nt < 4; ++nt) {
            int prow = 64 * wn + 16 * nt + pl;
            int phys = (prow + (g << 4)) & 127;
            bfr[nt] = *(const short8*)((const char*)Bs + g * 2048 + phys * 16);
        }
        #pragma unroll
        for (int mt = 0; mt < 4; ++mt)
            #pragma unroll
            for (int nt = 0; nt < 4; ++nt)
                acc[mt][nt] = __builtin_amdgcn_mfma_f32_16x16x32_bf16(afr[mt], bfr[nt], acc[mt][nt], 0, 0, 0);
        __syncthreads();
    }

    if (MODE == 1) {
        #pragma unroll
        for (int mt = 0; mt < 4; ++mt)
            #pragma unroll
            for (int r = 0; r < 4; ++r) {
                int row = m0 + 64 * wm + 16 * mt + 4 * g + r;
                float bb = bias[row];
                #pragma unroll
                for (int nt = 0; nt < 4; ++nt) {
                    int col = n0 + 64 * wn + 16 * nt + pl;
                    ((unsigned short*)outv)[((long)b * M + row) * HW + col] =
                        pack_bf16(acc[mt][nt][r] + bb);
                }
            }
    } else {
        // rows interleaved c*4+gate: one thread's f32x4 = all 4 gates of channel c
        const float4* bias4 = (const float4*)bias;
        unsigned short* Hp = (unsigned short*)outv;
        #pragma unroll
        for (int mt = 0; mt < 4; ++mt) {
            int c = (m0 >> 2) + 16 * wm + 4 * mt + g;
            float4 bb = bias4[c];
            #pragma unroll
            for (int nt = 0; nt < 4; ++nt) {
                int p = n0 + 64 * wn + 16 * nt + pl;
                long lidx = (long)b * PIX + (long)c * HW + p;       // linear (f32 state)
                long widx = (long)b * WI16 + bidx16(p, c, 4);       // u16 image
                float v0 = acc[mt][nt][0] + bb.x;
                float v1 = acc[mt][nt][1] + bb.y;
                float v2 = acc[mt][nt][2] + bb.z;
                float v3 = acc[mt][nt][3] + bb.w;
                if (MODE == 2) {
                    float* Cst = (float*)stv;
                    float cc = Cst[lidx] * sigf(v0) + sigf(v1) * tanhf_fast(v2);
                    Cst[lidx] = cc;
                    Hp[widx] = pack_bf16(sigf(v3) * tanhf_fast(cc));
                } else {
                    float* mpf = (float*)stv;
                    float ot = sigf(v0), gt = tanhf_fast(v1), it = sigf(v2);
                    float mo = mpf[lidx];
                    float mn = gt * it + (1.0f - it) * mo;
                    mpf[lidx] = mn;
                    simg[widx] = pack_bf16(mn);
                    float hv = ot * mn;
                    Hp[widx] = pack_bf16(hv);
                    if (Hout) Hout[lidx] = hv;
                }
            }
        }
    }
}

// ---------------- attention: VKM bf16 [16][640][1024] -> Zimg v3 (u16 bf16) ----------------
// block = (b, c-quad): 4 channels per block, dense uint2 stores
__global__ __launch_bounds__(1024) void attn_kernel(
    const unsigned short* __restrict__ VKM, unsigned short* __restrict__ Zimg)
{
    __shared__ float qs[4][32 * 33];
    const int tid = threadIdx.x;
    const int b = blockIdx.x >> 5, cq = blockIdx.x & 31;
    const int c0 = cq << 2;
    const long base = (long)b * 640 * HW;

    #pragma unroll
    for (int cc = 0; cc < 4; ++cc)
        qs[cc][(tid >> 5) * 33 + (tid & 31)] =
            bf16f(VKM[base + (long)(256 + c0 + cc) * HW + tid]);
    __syncthreads();

    const int i = tid >> 5, j = tid & 31;
    unsigned short zh[4], zm[4];
    #pragma unroll
    for (int cc = 0; cc < 4; ++cc) {
        const long cbs = base + (long)(c0 + cc) * HW;
        float qhT = qs[cc][j * 33 + i];
        float vh  = bf16f(VKM[cbs + tid]);
        float kh  = bf16f(VKM[cbs + 128l * HW + tid]);
        float km  = bf16f(VKM[cbs + 384l * HW + tid]);
        float vm  = bf16f(VKM[cbs + 512l * HW + tid]);

        float sh = kh * qhT, sm = qhT * km;
        float mh = sh, mm = sm;
        #pragma unroll
        for (int o = 16; o > 0; o >>= 1) {
            mh = fmaxf(mh, __shfl_xor(mh, o, 32));
            mm = fmaxf(mm, __shfl_xor(mm, o, 32));
        }
        float eh = __expf(sh - mh), em = __expf(sm - mm);
        float s1 = eh, s2 = em;
        #pragma unroll
        for (int o = 16; o > 0; o >>= 1) {
            s1 += __shfl_xor(s1, o, 32);
            s2 += __shfl_xor(s2, o, 32);
        }
        zh[cc] = pack_bf16(vh * (eh / s1));
        zm[cc] = pack_bf16(vm * (em / s2));
    }
    // zh at k=c0..c0+3 (ktile c0>>5), zm at k=c0+128 (ktile +4); 4 u16 = one uint2
    const int kt = c0 >> 5, kb = (c0 >> 3) & 3, sl = c0 & 7;
    const int phys = ((tid & 127) + (kb << 4)) & 127;
    long e16 = (long)b * WZ16 + ((long)((tid >> 7) * 8 + kt) << 12) +
               (kb << 10) + (phys << 3) + sl;
    uint2 oh, om;
    oh.x = (unsigned)zh[0] | ((unsigned)zh[1] << 16);
    oh.y = (unsigned)zh[2] | ((unsigned)zh[3] << 16);
    om.x = (unsigned)zm[0] | ((unsigned)zm[1] << 16);
    om.y = (unsigned)zm[2] | ((unsigned)zm[3] << 16);
    *(uint2*)(Zimg + e16)              = oh;
    *(uint2*)(Zimg + e16 + (4l << 12)) = om;
}

// ---------------- pack x into v3 bf16 image: dest-linear streaming ----------------
// one thread = one uint4 = 8 u16 = one row's 8 channels of one kblock.
// x layout is [B][T][C][HW] (batch-major)
__global__ __launch_bounds__(256) void pack_x(
    const float* __restrict__ x, uint4* __restrict__ Xp, int tstart, int oneshot)
{
    long q = (long)blockIdx.x * 256 + threadIdx.x;
    long e = q << 3;                        // u16 index
    int t = tstart + (int)(e >> 21);
    long r = e & ((1l << 21) - 1);
    int b = (int)(r >> 17);
    int v = (int)(r & ((1 << 17) - 1));     // u16 within batch image
    int tile = v >> 12;                     // ptile*4 + ktile
    int pt = tile >> 2, kt = tile & 3;
    int ww = v & 4095;
    int kb = ww >> 10, phys = (ww >> 3) & 127;
    int row = (phys - (kb << 4)) & 127;
    int p = (pt << 7) + row;
    int c = (kt << 5) + (kb << 3);
    const float* xs = x + (((long)b * TT + t) * CC + c) * HW + p;
    union { unsigned short s[8]; uint4 u; } o;
    #pragma unroll
    for (int jj = 0; jj < 8; ++jj)
        o.s[jj] = pack_bf16(xs[(long)jj * HW]);
    Xp[oneshot ? q : (q & ((1l << 18) - 1))] = o.u;
}

// ---------------- one-shot setup: build v3 bf16 weight tile images ----------------
__device__ __forceinline__ void wimg(unsigned short* img, int Ktiles, int r, int k, float v) {
    int tile = (r >> 7) * Ktiles + (k >> 5);
    int row = r & 127, ks = k & 31;
    int kb = ks >> 3;
    int phys = (row + (kb << 4)) & 127;
    img[(size_t)tile * TW16 + (kb << 10) + (phys << 3) + (ks & 7)] = pack_bf16(v);
}

__global__ __launch_bounds__(256) void setup_all(
    const float* __restrict__ W5, const float* __restrict__ W8, const float* __restrict__ b8,
    unsigned short* __restrict__ Wp5i,
    unsigned short* __restrict__ Wgi, float* __restrict__ bg4,
    unsigned short* __restrict__ Woi, float* __restrict__ bo4)
{
    int idx = blockIdx.x * 256 + threadIdx.x;
    if (idx < 81920) {                       // W5 [640][128] -> Wp5 image (Ktiles=4)
        int r = idx >> 7, k = idx & 127;
        wimg(Wp5i, 4, r, k, W5[idx]);
        return;
    }
    idx -= 81920;
    if (idx < 131072) {                      // Wg: rows c*4+gate, convs 10..13, K=256 (Ktiles=8)
        int rr = idx >> 8, k = idx & 255;
        int c = rr >> 2, gg = rr & 3;
        wimg(Wgi, 8, rr, k, W8[((long)(4 + gg) * 128 + c) * 256 + k]);
        if (k == 0) bg4[rr] = b8[(4 + gg) * 128 + c];
        return;
    }
    idx -= 131072;                           // Wo: 512 rows x 384, conv6 folded (Ktiles=12)
    if (idx >= 512 * 384) return;
    int rr = idx / 384, k = idx - rr * 384;
    int c = rr >> 2, gg = rr & 3;
    float wv = 0.0f;
    if (gg < 3) {
        const float* wr = W8 + ((long)(1 + gg) * 128 + c) * 256;
        if (k < 128) {
            wv = wr[k];
        } else {
            int i = k - 128;
            float s = 0.0f;
            for (int j = 0; j < 128; ++j)
                s += wr[128 + j] * W8[(long)j * 256 + i];   // Wz = W8[0]
            wv = s;
        }
    }
    wimg(Woi, 12, rr, k, wv);
    if (k == 0) {
        float bb = 0.0f;
        if (gg < 3) {
            bb = b8[(1 + gg) * 128 + c];
            const float* wr = W8 + ((long)(1 + gg) * 128 + c) * 256;
            for (int j = 0; j < 128; ++j) bb += wr[128 + j] * b8[j];  // bz = b8[0]
        }
        bo4[rr] = bb;
    }
}

extern "C" void kernel_launch(void* const* d_in, const int* in_sizes, int n_in,
                              void* d_out, int out_size, void* d_ws, size_t ws_size,
                              hipStream_t stream)
{
    const float* x  = (const float*)d_in[0];   // [16][16][128][1024]  (B-major)
    const float* c0 = (const float*)d_in[1];
    const float* W5 = (const float*)d_in[2];   // [640][128]
    const float* b5 = (const float*)d_in[3];   // [640]
    const float* W8 = (const float*)d_in[4];   // [8][128][256]
    const float* b8 = (const float*)d_in[5];   // [8][128]
    float* out = (float*)d_out;

    const long S = STOT;
    unsigned short* Ha  = (unsigned short*)d_ws;        // 16*WI16 u16 image
    unsigned short* Hb  = Ha + 16l * WI16;              // 16*WI16
    unsigned short* mpi = Hb + 16l * WI16;              // 16*WI16 (mp bf16 image)
    float* mpf = (float*)(mpi + 16l * WI16);            // S fp32 (mp full state)
    float* Cst = mpf + S;                               // S fp32
    unsigned short* Wp5i = (unsigned short*)(Cst + S);  // 20 tiles * 4096 u16
    unsigned short* Wgi  = Wp5i + 20 * TW16;            // 32 tiles
    unsigned short* Woi  = Wgi + 32 * TW16;             // 48 tiles
    float* bg4 = (float*)(Woi + 48 * TW16);             // 512
    float* bo4 = bg4 + 512;                             // 512
    unsigned short* VKM  = (unsigned short*)(bo4 + 512);   // 5S bf16 linear
    unsigned short* Zimg = VKM + 5 * S;                    // 16*WZ16 u16 image
    unsigned short* Xp   = Zimg + 16l * WZ16;              // 16*XW16 full, or XW16 slot

    const bool havex =
        ((char*)(Xp + 16l * XW16) - (char*)d_ws) <= (long)ws_size;

    hipMemsetAsync(Hb,  0, 16l * WI16 * 2, stream);
    hipMemsetAsync(mpi, 0, 16l * WI16 * 2, stream);
    hipMemsetAsync(mpf, 0, S * sizeof(float), stream);
    hipMemcpyAsync(Cst, c0, S * sizeof(float), hipMemcpyDeviceToDevice, stream);

    setup_all<<<1600, dim3(256), 0, stream>>>(W5, W8, b8, Wp5i, Wgi, bg4, Woi, bo4);
    if (havex)
        pack_x<<<16384, dim3(256), 0, stream>>>(x, (uint4*)Xp, 0, 1);

    const int BIG = 1 << 30;
    const dim3 blk(256);
    for (int t = 0; t < TT; ++t) {
        if (!havex)
            pack_x<<<1024, dim3(256), 0, stream>>>(x, (uint4*)Xp, t, 0);
        const unsigned short* Xpt = Xp + (havex ? (long)t * XW16 : 0l);

        // gates = Wg * [Hb ; x_t], fused LSTM -> Cst, Ha image  (M=512, K=256)
        gemm_mfma<2><<<dim3(8, 4, 16), blk, 0, stream>>>(
            Wgi, bg4, Hb, (long)WI16, Xpt, (long)WI16, 4,
            128, BIG, Ha, Cst, nullptr, nullptr, 512, 256);

        // vh,kh,qh (Ha) + km,vm (mpi)   (M=640, K=128) -> VKM bf16 linear
        gemm_mfma<1><<<dim3(8, 5, 16), blk, 0, stream>>>(
            Wp5i, b5, Ha, (long)WI16, mpi, (long)WI16, 4,
            BIG, 384, VKM, nullptr, nullptr, nullptr, 640, 128);

        attn_kernel<<<512, dim3(1024), 0, stream>>>(VKM, Zimg);

        // o,g,i = Wo * [Ha ; Zimg] (conv6 folded), fused final -> mpf/mpi, Hb (+out)
        gemm_mfma<3><<<dim3(8, 4, 16), blk, 0, stream>>>(
            Woi, bo4, Ha, (long)WI16, Zimg, (long)WZ16, 8,
            128, BIG, Hb, mpf, mpi, (t == TT - 1) ? out : nullptr, 512, 384);
    }
}

// Round 12
// 1085.184 us; speedup vs baseline: 9.7994x; 1.0341x over previous
//
#include <hip/hip_runtime.h>
#include <hip/hip_bf16.h>

#define BB 16
#define TT 16
#define CC 128
#define HW 1024             // 32*32
#define PIX (CC*HW)         // 131072
#define STOT ((long)BB*PIX) // 2M

// image geometry v3 (A and B): tiles of 128 rows x 32 k, u16 bf16, kblock-major (8 ch),
// a16(row,k) = (k>>3)*1024 + phys*8 + (k&7), phys = (row + 16*(k>>3)) & 127
#define TW16 4096           // u16 per tile (8192 B)
#define WI16 131072         // u16 per batch, K=128 image (8 ptiles * 4 ktiles)
#define WZ16 262144         // u16 per batch, K=256 image (ZHZM)
#define XW16 2097152        // u16 per timestep of Xp (16 batches * WI16)

typedef short short8 __attribute__((ext_vector_type(8)));
typedef float f32x4  __attribute__((ext_vector_type(4)));

__device__ __forceinline__ float sigf(float x) { return 1.0f / (1.0f + __expf(-x)); }
__device__ __forceinline__ float tanhf_fast(float x) {
    float ax = fabsf(x);
    float t = __expf(-2.0f * ax);
    float r = (1.0f - t) / (1.0f + t);
    return copysignf(r, x);
}

__device__ __forceinline__ unsigned short pack_bf16(float x) {
    unsigned u = __float_as_uint(x);
    return (unsigned short)((u + 0x7fffu + ((u >> 16) & 1u)) >> 16);
}
__device__ __forceinline__ float bf16f(unsigned short s) {
    return __uint_as_float(((unsigned)s) << 16);
}

// u16 index of element (pixel p, k-channel c) in a per-batch v3 image with nkt k-tiles
__device__ __forceinline__ long bidx16(int p, int c, int nkt) {
    int kb = (c >> 3) & 3;
    int phys = ((p & 127) + (kb << 4)) & 127;
    return ((long)((p >> 7) * nkt + (c >> 5)) << 12) + (kb << 10) + (phys << 3) + (c & 7);
}

typedef __attribute__((address_space(3))) unsigned lds_u32_t;
typedef __attribute__((address_space(1))) const unsigned gbl_u32_t;
__device__ __forceinline__ void gld16(const void* g, unsigned* l) {
    __builtin_amdgcn_global_load_lds((gbl_u32_t*)g, (lds_u32_t*)l, 16, 0, 0);
}

// ---------------- MFMA GEMM, fused epilogues; 1-pass bf16, BK=64 double-buffered ----------------
// MODE 1: bf16 store (+ scalar bias[row])  -> outv = ushort* (linear)
// MODE 2: LSTM fuse: stv=Cst(f32 linear), outv=Ha image (u16)
// MODE 3: final fuse: stv=mpf(f32 linear), simg=mp image(u16), outv=Hb image(u16), Hout opt
// B-source per 32-chunk: m0>=m_split -> imgB(kofs 0); k>=k_split -> imgB(kofs k_split); else imgA.
// Pipeline: one barrier per 64-K iter; stage(it+1) DMA issued right after the barrier,
// in flight under this iter's 32 MFMA + ds_reads. K must be a multiple of 64 (128/256/384 ok).
template<int MODE>
__global__ __launch_bounds__(256, 2) void gemm_mfma(
    const unsigned short* __restrict__ Wp, const float* __restrict__ bias,
    const unsigned short* __restrict__ imgA, long wA,
    const unsigned short* __restrict__ imgB, long wB, int nktB,
    int k_split, int m_split,
    void* __restrict__ outv, void* __restrict__ stv,
    unsigned short* __restrict__ simg, float* __restrict__ Hout,
    int M, int K)
{
    __shared__ __align__(16) unsigned As[2][4096];   // 2 x 16 KB (two 8 KB k-chunks)
    __shared__ __align__(16) unsigned Bs[2][4096];   // 2 x 16 KB

    const int b  = blockIdx.z;
    const int n0 = blockIdx.x * 128;
    const int m0 = blockIdx.y * 128;
    const int t  = threadIdx.x;
    const int lane = t & 63;
    const int w  = t >> 6;
    const int wm = w & 1, wn = w >> 1;
    const int g  = lane >> 4, pl = lane & 15;
    const int nk64 = K >> 6;

    f32x4 acc[4][4] = {};

    auto stageA = [&](int kchunk, unsigned* dst) {
        const char* gA = (const char*)(Wp +
            (size_t)((m0 >> 7) * (K >> 5) + (kchunk >> 5)) * TW16);
        gld16(gA + t * 16, dst + t * 4);
        gld16(gA + 4096 + t * 16, dst + 1024 + t * 4);
    };
    auto stageB = [&](int kchunk, unsigned* dst) {
        const bool useB = (m0 >= m_split) || (kchunk >= k_split);
        const int kc = useB ? (kchunk - ((m0 >= m_split) ? 0 : k_split)) : kchunk;
        const unsigned short* img = useB ? imgB : imgA;
        const long bw = useB ? wB : wA;
        const int nkt = useB ? nktB : 4;
        const char* gB = (const char*)(img + (long)b * bw +
            ((long)((n0 >> 7) * nkt + (kc >> 5)) << 12));
        gld16(gB + t * 16, dst + t * 4);
        gld16(gB + 4096 + t * 16, dst + 1024 + t * 4);
    };
    auto stage = [&](int k0, int buf) {
        stageA(k0,      As[buf]);
        stageA(k0 + 32, As[buf] + 2048);
        stageB(k0,      Bs[buf]);
        stageB(k0 + 32, Bs[buf] + 2048);
    };

    stage(0, 0);                                   // prologue

    for (int it = 0; it < nk64; ++it) {
        const int buf = it & 1;
        __syncthreads();                           // drains stage(it); prev compute done
        if (it + 1 < nk64) stage((it + 1) << 6, buf ^ 1);   // DMA under MFMA

        #pragma unroll
        for (int h = 0; h < 2; ++h) {
            short8 afr[4], bfr[4];
            #pragma unroll
            for (int mt = 0; mt < 4; ++mt) {
                int row = 64 * wm + 16 * mt + pl;
                int phys = (row + (g << 4)) & 127;
                afr[mt] = *(const short8*)((const char*)As[buf] + h * 8192 + g * 2048 + phys * 16);
            }
            #pragma unroll
            for (int nt = 0; nt < 4; ++nt) {
                int prow = 64 * wn + 16 * nt + pl;
                int phys = (prow + (g << 4)) & 127;
                bfr[nt] = *(const short8*)((const char*)Bs[buf] + h * 8192 + g * 2048 + phys * 16);
            }
            #pragma unroll
            for (int mt = 0; mt < 4; ++mt)
                #pragma unroll
                for (int nt = 0; nt < 4; ++nt)
                    acc[mt][nt] = __builtin_amdgcn_mfma_f32_16x16x32_bf16(afr[mt], bfr[nt], acc[mt][nt], 0, 0, 0);
        }
    }

    if (MODE == 1) {
        #pragma unroll
        for (int mt = 0; mt < 4; ++mt)
            #pragma unroll
            for (int r = 0; r < 4; ++r) {
                int row = m0 + 64 * wm + 16 * mt + 4 * g + r;
                float bb = bias[row];
                #pragma unroll
                for (int nt = 0; nt < 4; ++nt) {
                    int col = n0 + 64 * wn + 16 * nt + pl;
                    ((unsigned short*)outv)[((long)b * M + row) * HW + col] =
                        pack_bf16(acc[mt][nt][r] + bb);
                }
            }
    } else {
        // rows interleaved c*4+gate: one thread's f32x4 = all 4 gates of channel c
        const float4* bias4 = (const float4*)bias;
        unsigned short* Hp = (unsigned short*)outv;
        #pragma unroll
        for (int mt = 0; mt < 4; ++mt) {
            int c = (m0 >> 2) + 16 * wm + 4 * mt + g;
            float4 bb = bias4[c];
            #pragma unroll
            for (int nt = 0; nt < 4; ++nt) {
                int p = n0 + 64 * wn + 16 * nt + pl;
                long lidx = (long)b * PIX + (long)c * HW + p;       // linear (f32 state)
                long widx = (long)b * WI16 + bidx16(p, c, 4);       // u16 image
                float v0 = acc[mt][nt][0] + bb.x;
                float v1 = acc[mt][nt][1] + bb.y;
                float v2 = acc[mt][nt][2] + bb.z;
                float v3 = acc[mt][nt][3] + bb.w;
                if (MODE == 2) {
                    float* Cst = (float*)stv;
                    float cc = Cst[lidx] * sigf(v0) + sigf(v1) * tanhf_fast(v2);
                    Cst[lidx] = cc;
                    Hp[widx] = pack_bf16(sigf(v3) * tanhf_fast(cc));
                } else {
                    float* mpf = (float*)stv;
                    float ot = sigf(v0), gt = tanhf_fast(v1), it2 = sigf(v2);
                    float mo = mpf[lidx];
                    float mn = gt * it2 + (1.0f - it2) * mo;
                    mpf[lidx] = mn;
                    simg[widx] = pack_bf16(mn);
                    float hv = ot * mn;
                    Hp[widx] = pack_bf16(hv);
                    if (Hout) Hout[lidx] = hv;
                }
            }
        }
    }
}

// ---------------- attention: VKM bf16 [16][640][1024] -> Zimg v3 (u16 bf16) ----------------
// block = (b, c-quad): 4 channels per block, dense uint2 stores
__global__ __launch_bounds__(1024) void attn_kernel(
    const unsigned short* __restrict__ VKM, unsigned short* __restrict__ Zimg)
{
    __shared__ float qs[4][32 * 33];
    const int tid = threadIdx.x;
    const int b = blockIdx.x >> 5, cq = blockIdx.x & 31;
    const int c0 = cq << 2;
    const long base = (long)b * 640 * HW;

    #pragma unroll
    for (int cc = 0; cc < 4; ++cc)
        qs[cc][(tid >> 5) * 33 + (tid & 31)] =
            bf16f(VKM[base + (long)(256 + c0 + cc) * HW + tid]);
    __syncthreads();

    const int i = tid >> 5, j = tid & 31;
    unsigned short zh[4], zm[4];
    #pragma unroll
    for (int cc = 0; cc < 4; ++cc) {
        const long cbs = base + (long)(c0 + cc) * HW;
        float qhT = qs[cc][j * 33 + i];
        float vh  = bf16f(VKM[cbs + tid]);
        float kh  = bf16f(VKM[cbs + 128l * HW + tid]);
        float km  = bf16f(VKM[cbs + 384l * HW + tid]);
        float vm  = bf16f(VKM[cbs + 512l * HW + tid]);

        float sh = kh * qhT, sm = qhT * km;
        float mh = sh, mm = sm;
        #pragma unroll
        for (int o = 16; o > 0; o >>= 1) {
            mh = fmaxf(mh, __shfl_xor(mh, o, 32));
            mm = fmaxf(mm, __shfl_xor(mm, o, 32));
        }
        float eh = __expf(sh - mh), em = __expf(sm - mm);
        float s1 = eh, s2 = em;
        #pragma unroll
        for (int o = 16; o > 0; o >>= 1) {
            s1 += __shfl_xor(s1, o, 32);
            s2 += __shfl_xor(s2, o, 32);
        }
        zh[cc] = pack_bf16(vh * (eh / s1));
        zm[cc] = pack_bf16(vm * (em / s2));
    }
    // zh at k=c0..c0+3 (ktile c0>>5), zm at k=c0+128 (ktile +4); 4 u16 = one uint2
    const int kt = c0 >> 5, kb = (c0 >> 3) & 3, sl = c0 & 7;
    const int phys = ((tid & 127) + (kb << 4)) & 127;
    long e16 = (long)b * WZ16 + ((long)((tid >> 7) * 8 + kt) << 12) +
               (kb << 10) + (phys << 3) + sl;
    uint2 oh, om;
    oh.x = (unsigned)zh[0] | ((unsigned)zh[1] << 16);
    oh.y = (unsigned)zh[2] | ((unsigned)zh[3] << 16);
    om.x = (unsigned)zm[0] | ((unsigned)zm[1] << 16);
    om.y = (unsigned)zm[2] | ((unsigned)zm[3] << 16);
    *(uint2*)(Zimg + e16)              = oh;
    *(uint2*)(Zimg + e16 + (4l << 12)) = om;
}

// ---------------- pack x into v3 bf16 image: dest-linear streaming ----------------
// one thread = one uint4 = 8 u16 = one row's 8 channels of one kblock.
// x layout is [B][T][C][HW] (batch-major)
__global__ __launch_bounds__(256) void pack_x(
    const float* __restrict__ x, uint4* __restrict__ Xp, int tstart, int oneshot)
{
    long q = (long)blockIdx.x * 256 + threadIdx.x;
    long e = q << 3;                        // u16 index
    int t = tstart + (int)(e >> 21);
    long r = e & ((1l << 21) - 1);
    int b = (int)(r >> 17);
    int v = (int)(r & ((1 << 17) - 1));     // u16 within batch image
    int tile = v >> 12;                     // ptile*4 + ktile
    int pt = tile >> 2, kt = tile & 3;
    int ww = v & 4095;
    int kb = ww >> 10, phys = (ww >> 3) & 127;
    int row = (phys - (kb << 4)) & 127;
    int p = (pt << 7) + row;
    int c = (kt << 5) + (kb << 3);
    const float* xs = x + (((long)b * TT + t) * CC + c) * HW + p;
    union { unsigned short s[8]; uint4 u; } o;
    #pragma unroll
    for (int jj = 0; jj < 8; ++jj)
        o.s[jj] = pack_bf16(xs[(long)jj * HW]);
    Xp[oneshot ? q : (q & ((1l << 18) - 1))] = o.u;
}

// ---------------- one-shot setup: build v3 bf16 weight tile images ----------------
__device__ __forceinline__ void wimg(unsigned short* img, int Ktiles, int r, int k, float v) {
    int tile = (r >> 7) * Ktiles + (k >> 5);
    int row = r & 127, ks = k & 31;
    int kb = ks >> 3;
    int phys = (row + (kb << 4)) & 127;
    img[(size_t)tile * TW16 + (kb << 10) + (phys << 3) + (ks & 7)] = pack_bf16(v);
}

__global__ __launch_bounds__(256) void setup_all(
    const float* __restrict__ W5, const float* __restrict__ W8, const float* __restrict__ b8,
    unsigned short* __restrict__ Wp5i,
    unsigned short* __restrict__ Wgi, float* __restrict__ bg4,
    unsigned short* __restrict__ Woi, float* __restrict__ bo4)
{
    int idx = blockIdx.x * 256 + threadIdx.x;
    if (idx < 81920) {                       // W5 [640][128] -> Wp5 image (Ktiles=4)
        int r = idx >> 7, k = idx & 127;
        wimg(Wp5i, 4, r, k, W5[idx]);
        return;
    }
    idx -= 81920;
    if (idx < 131072) {                      // Wg: rows c*4+gate, convs 10..13, K=256 (Ktiles=8)
        int rr = idx >> 8, k = idx & 255;
        int c = rr >> 2, gg = rr & 3;
        wimg(Wgi, 8, rr, k, W8[((long)(4 + gg) * 128 + c) * 256 + k]);
        if (k == 0) bg4[rr] = b8[(4 + gg) * 128 + c];
        return;
    }
    idx -= 131072;                           // Wo: 512 rows x 384, conv6 folded (Ktiles=12)
    if (idx >= 512 * 384) return;
    int rr = idx / 384, k = idx - rr * 384;
    int c = rr >> 2, gg = rr & 3;
    float wv = 0.0f;
    if (gg < 3) {
        const float* wr = W8 + ((long)(1 + gg) * 128 + c) * 256;
        if (k < 128) {
            wv = wr[k];
        } else {
            int i = k - 128;
            float s = 0.0f;
            for (int j = 0; j < 128; ++j)
                s += wr[128 + j] * W8[(long)j * 256 + i];   // Wz = W8[0]
            wv = s;
        }
    }
    wimg(Woi, 12, rr, k, wv);
    if (k == 0) {
        float bb = 0.0f;
        if (gg < 3) {
            bb = b8[(1 + gg) * 128 + c];
            const float* wr = W8 + ((long)(1 + gg) * 128 + c) * 256;
            for (int j = 0; j < 128; ++j) bb += wr[128 + j] * b8[j];  // bz = b8[0]
        }
        bo4[rr] = bb;
    }
}

extern "C" void kernel_launch(void* const* d_in, const int* in_sizes, int n_in,
                              void* d_out, int out_size, void* d_ws, size_t ws_size,
                              hipStream_t stream)
{
    const float* x  = (const float*)d_in[0];   // [16][16][128][1024]  (B-major)
    const float* c0 = (const float*)d_in[1];
    const float* W5 = (const float*)d_in[2];   // [640][128]
    const float* b5 = (const float*)d_in[3];   // [640]
    const float* W8 = (const float*)d_in[4];   // [8][128][256]
    const float* b8 = (const float*)d_in[5];   // [8][128]
    float* out = (float*)d_out;

    const long S = STOT;
    unsigned short* Ha  = (unsigned short*)d_ws;        // 16*WI16 u16 image
    unsigned short* Hb  = Ha + 16l * WI16;              // 16*WI16
    unsigned short* mpi = Hb + 16l * WI16;              // 16*WI16 (mp bf16 image)
    float* mpf = (float*)(mpi + 16l * WI16);            // S fp32 (mp full state)
    float* Cst = mpf + S;                               // S fp32
    unsigned short* Wp5i = (unsigned short*)(Cst + S);  // 20 tiles * 4096 u16
    unsigned short* Wgi  = Wp5i + 20 * TW16;            // 32 tiles
    unsigned short* Woi  = Wgi + 32 * TW16;             // 48 tiles
    float* bg4 = (float*)(Woi + 48 * TW16);             // 512
    float* bo4 = bg4 + 512;                             // 512
    unsigned short* VKM  = (unsigned short*)(bo4 + 512);   // 5S bf16 linear
    unsigned short* Zimg = VKM + 5 * S;                    // 16*WZ16 u16 image
    unsigned short* Xp   = Zimg + 16l * WZ16;              // 16*XW16 full, or XW16 slot

    const bool havex =
        ((char*)(Xp + 16l * XW16) - (char*)d_ws) <= (long)ws_size;

    hipMemsetAsync(Hb,  0, 16l * WI16 * 2, stream);
    hipMemsetAsync(mpi, 0, 16l * WI16 * 2, stream);
    hipMemsetAsync(mpf, 0, S * sizeof(float), stream);
    hipMemcpyAsync(Cst, c0, S * sizeof(float), hipMemcpyDeviceToDevice, stream);

    setup_all<<<1600, dim3(256), 0, stream>>>(W5, W8, b8, Wp5i, Wgi, bg4, Woi, bo4);
    if (havex)
        pack_x<<<16384, dim3(256), 0, stream>>>(x, (uint4*)Xp, 0, 1);

    const int BIG = 1 << 30;
    const dim3 blk(256);
    for (int t = 0; t < TT; ++t) {
        if (!havex)
            pack_x<<<1024, dim3(256), 0, stream>>>(x, (uint4*)Xp, t, 0);
        const unsigned short* Xpt = Xp + (havex ? (long)t * XW16 : 0l);

        // gates = Wg * [Hb ; x_t], fused LSTM -> Cst, Ha image  (M=512, K=256)
        gemm_mfma<2><<<dim3(8, 4, 16), blk, 0, stream>>>(
            Wgi, bg4, Hb, (long)WI16, Xpt, (long)WI16, 4,
            128, BIG, Ha, Cst, nullptr, nullptr, 512, 256);

        // vh,kh,qh (Ha) + km,vm (mpi)   (M=640, K=128) -> VKM bf16 linear
        gemm_mfma<1><<<dim3(8, 5, 16), blk, 0, stream>>>(
            Wp5i, b5, Ha, (long)WI16, mpi, (long)WI16, 4,
            BIG, 384, VKM, nullptr, nullptr, nullptr, 640, 128);

        attn_kernel<<<512, dim3(1024), 0, stream>>>(VKM, Zimg);

        // o,g,i = Wo * [Ha ; Zimg] (conv6 folded), fused final -> mpf/mpi, Hb (+out)
        gemm_mfma<3><<<dim3(8, 4, 16), blk, 0, stream>>>(
            Woi, bo4, Ha, (long)WI16, Zimg, (long)WZ16, 8,
            128, BIG, Hb, mpf, mpi, (t == TT - 1) ? out : nullptr, 512, 384);
    }
}

// Round 13
// 1049.699 us; speedup vs baseline: 10.1306x; 1.0338x over previous
//
#include <hip/hip_runtime.h>
#include <hip/hip_bf16.h>

#define BB 16
#define TT 16
#define CC 128
#define HW 1024             // 32*32
#define PIX (CC*HW)         // 131072
#define STOT ((long)BB*PIX) // 2M

// image geometry v3 (A and B): tiles of 128 rows x 32 k, u16 bf16, kblock-major (8 ch),
// a16(row,k) = (k>>3)*1024 + phys*8 + (k&7), phys = (row + 16*(k>>3)) & 127
#define TW16 4096           // u16 per tile (8192 B)
#define WI16 131072         // u16 per batch, K=128 image (8 ptiles * 4 ktiles)
#define WZ16 262144         // u16 per batch, K=256 image (ZHZM)
#define XW16 2097152        // u16 per timestep of Xp (16 batches * WI16)
// VKM v2: u16 elem (b,row,p) at ((b*160 + (row>>2))*1024 + p)*4 + (row&3)

typedef short short8 __attribute__((ext_vector_type(8)));
typedef float f32x4  __attribute__((ext_vector_type(4)));

__device__ __forceinline__ float sigf(float x) { return 1.0f / (1.0f + __expf(-x)); }
__device__ __forceinline__ float tanhf_fast(float x) {
    float ax = fabsf(x);
    float t = __expf(-2.0f * ax);
    float r = (1.0f - t) / (1.0f + t);
    return copysignf(r, x);
}

__device__ __forceinline__ unsigned short pack_bf16(float x) {
    unsigned u = __float_as_uint(x);
    return (unsigned short)((u + 0x7fffu + ((u >> 16) & 1u)) >> 16);
}
__device__ __forceinline__ float bf16f(unsigned s) {
    return __uint_as_float(s << 16);
}

// u16 index of element (pixel p, k-channel c) in a per-batch v3 image with nkt k-tiles
__device__ __forceinline__ long bidx16(int p, int c, int nkt) {
    int kb = (c >> 3) & 3;
    int phys = ((p & 127) + (kb << 4)) & 127;
    return ((long)((p >> 7) * nkt + (c >> 5)) << 12) + (kb << 10) + (phys << 3) + (c & 7);
}

typedef __attribute__((address_space(3))) unsigned lds_u32_t;
typedef __attribute__((address_space(1))) const unsigned gbl_u32_t;
__device__ __forceinline__ void gld16(const void* g, unsigned* l) {
    __builtin_amdgcn_global_load_lds((gbl_u32_t*)g, (lds_u32_t*)l, 16, 0, 0);
}

// ---------------- MFMA GEMM, fused epilogues; 1-pass bf16, BK=64 double-buffered ----------------
// MODE 1: VKM v2 store (+ bias4[rq]) -> outv = uint2* (row-quad interleaved)
// MODE 2: LSTM fuse: stv=Cst(f32 linear), outv=Ha image (u16)
// MODE 3: final fuse: stv=mpf(f32 linear), simg=mp image(u16), outv=Hb image(u16), Hout opt
// B-source per 32-chunk: m0>=m_split -> imgB(kofs 0); k>=k_split -> imgB(kofs k_split); else imgA.
// Pipeline: one barrier per 64-K iter; stage(it+1) DMA issued right after the barrier,
// in flight under this iter's 32 MFMA + ds_reads. K must be a multiple of 64.
template<int MODE>
__global__ __launch_bounds__(256, 2) void gemm_mfma(
    const unsigned short* __restrict__ Wp, const float* __restrict__ bias,
    const unsigned short* __restrict__ imgA, long wA,
    const unsigned short* __restrict__ imgB, long wB, int nktB,
    int k_split, int m_split,
    void* __restrict__ outv, void* __restrict__ stv,
    unsigned short* __restrict__ simg, float* __restrict__ Hout,
    int M, int K)
{
    __shared__ __align__(16) unsigned As[2][4096];   // 2 x 16 KB (two 8 KB k-chunks)
    __shared__ __align__(16) unsigned Bs[2][4096];   // 2 x 16 KB

    const int b  = blockIdx.z;
    const int n0 = blockIdx.x * 128;
    const int m0 = blockIdx.y * 128;
    const int t  = threadIdx.x;
    const int lane = t & 63;
    const int w  = t >> 6;
    const int wm = w & 1, wn = w >> 1;
    const int g  = lane >> 4, pl = lane & 15;
    const int nk64 = K >> 6;

    f32x4 acc[4][4] = {};

    auto stageA = [&](int kchunk, unsigned* dst) {
        const char* gA = (const char*)(Wp +
            (size_t)((m0 >> 7) * (K >> 5) + (kchunk >> 5)) * TW16);
        gld16(gA + t * 16, dst + t * 4);
        gld16(gA + 4096 + t * 16, dst + 1024 + t * 4);
    };
    auto stageB = [&](int kchunk, unsigned* dst) {
        const bool useB = (m0 >= m_split) || (kchunk >= k_split);
        const int kc = useB ? (kchunk - ((m0 >= m_split) ? 0 : k_split)) : kchunk;
        const unsigned short* img = useB ? imgB : imgA;
        const long bw = useB ? wB : wA;
        const int nkt = useB ? nktB : 4;
        const char* gB = (const char*)(img + (long)b * bw +
            ((long)((n0 >> 7) * nkt + (kc >> 5)) << 12));
        gld16(gB + t * 16, dst + t * 4);
        gld16(gB + 4096 + t * 16, dst + 1024 + t * 4);
    };
    auto stage = [&](int k0, int buf) {
        stageA(k0,      As[buf]);
        stageA(k0 + 32, As[buf] + 2048);
        stageB(k0,      Bs[buf]);
        stageB(k0 + 32, Bs[buf] + 2048);
    };

    stage(0, 0);                                   // prologue

    for (int it = 0; it < nk64; ++it) {
        const int buf = it & 1;
        __syncthreads();                           // drains stage(it); prev compute done
        if (it + 1 < nk64) stage((it + 1) << 6, buf ^ 1);   // DMA under MFMA

        #pragma unroll
        for (int h = 0; h < 2; ++h) {
            short8 afr[4], bfr[4];
            #pragma unroll
            for (int mt = 0; mt < 4; ++mt) {
                int row = 64 * wm + 16 * mt + pl;
                int phys = (row + (g << 4)) & 127;
                afr[mt] = *(const short8*)((const char*)As[buf] + h * 8192 + g * 2048 + phys * 16);
            }
            #pragma unroll
            for (int nt = 0; nt < 4; ++nt) {
                int prow = 64 * wn + 16 * nt + pl;
                int phys = (prow + (g << 4)) & 127;
                bfr[nt] = *(const short8*)((const char*)Bs[buf] + h * 8192 + g * 2048 + phys * 16);
            }
            #pragma unroll
            for (int mt = 0; mt < 4; ++mt)
                #pragma unroll
                for (int nt = 0; nt < 4; ++nt)
                    acc[mt][nt] = __builtin_amdgcn_mfma_f32_16x16x32_bf16(afr[mt], bfr[nt], acc[mt][nt], 0, 0, 0);
        }
    }

    if (MODE == 1) {
        // VKM v2: one dense uint2 per (mt,nt) — rows 4*rq..4*rq+3 at one column
        const float4* b4 = (const float4*)bias;
        uint2* V2 = (uint2*)outv;
        #pragma unroll
        for (int mt = 0; mt < 4; ++mt) {
            int rq = (m0 >> 2) + 16 * wm + 4 * mt + g;
            float4 bb = b4[rq];
            #pragma unroll
            for (int nt = 0; nt < 4; ++nt) {
                int col = n0 + 64 * wn + 16 * nt + pl;
                uint2 o;
                o.x = (unsigned)pack_bf16(acc[mt][nt][0] + bb.x) |
                      ((unsigned)pack_bf16(acc[mt][nt][1] + bb.y) << 16);
                o.y = (unsigned)pack_bf16(acc[mt][nt][2] + bb.z) |
                      ((unsigned)pack_bf16(acc[mt][nt][3] + bb.w) << 16);
                V2[((long)b * (M >> 2) + rq) * 1024 + col] = o;
            }
        }
    } else {
        // rows interleaved c*4+gate: one thread's f32x4 = all 4 gates of channel c
        const float4* bias4 = (const float4*)bias;
        unsigned short* Hp = (unsigned short*)outv;
        #pragma unroll
        for (int mt = 0; mt < 4; ++mt) {
            int c = (m0 >> 2) + 16 * wm + 4 * mt + g;
            float4 bb = bias4[c];
            #pragma unroll
            for (int nt = 0; nt < 4; ++nt) {
                int p = n0 + 64 * wn + 16 * nt + pl;
                long lidx = (long)b * PIX + (long)c * HW + p;       // linear (f32 state)
                long widx = (long)b * WI16 + bidx16(p, c, 4);       // u16 image
                float v0 = acc[mt][nt][0] + bb.x;
                float v1 = acc[mt][nt][1] + bb.y;
                float v2 = acc[mt][nt][2] + bb.z;
                float v3 = acc[mt][nt][3] + bb.w;
                if (MODE == 2) {
                    float* Cst = (float*)stv;
                    float cc = Cst[lidx] * sigf(v0) + sigf(v1) * tanhf_fast(v2);
                    Cst[lidx] = cc;
                    Hp[widx] = pack_bf16(sigf(v3) * tanhf_fast(cc));
                } else {
                    float* mpf = (float*)stv;
                    float ot = sigf(v0), gt = tanhf_fast(v1), it2 = sigf(v2);
                    float mo = mpf[lidx];
                    float mn = gt * it2 + (1.0f - it2) * mo;
                    mpf[lidx] = mn;
                    simg[widx] = pack_bf16(mn);
                    float hv = ot * mn;
                    Hp[widx] = pack_bf16(hv);
                    if (Hout) Hout[lidx] = hv;
                }
            }
        }
    }
}

// ---------------- attention: VKM v2 (uint2) -> Zimg v3 (uint4) ----------------
// block = (b, c-oct): 8 channels per block; dense uint2 loads, dense uint4 stores.
// planes (rq base): vh=0, kh=32, qh=64, km=96, vm=128 (+q0, q0 = c0>>2)
__global__ __launch_bounds__(1024) void attn_kernel(
    const uint2* __restrict__ VKM2, uint4* __restrict__ Zimg4)
{
    __shared__ float qs[8][32 * 33];
    const int tid = threadIdx.x;
    const int b = blockIdx.x >> 4, c8 = blockIdx.x & 15;
    const int c0 = c8 << 3;
    const int q0 = c8 << 1;
    const long pb = (long)b * 160 * 1024;

    // stage qh^T for 8 channels
    {
        uint2 qa = VKM2[pb + (long)(64 + q0) * 1024 + tid];
        uint2 qb = VKM2[pb + (long)(65 + q0) * 1024 + tid];
        int ti = (tid & 31) * 33 + (tid >> 5);
        qs[0][ti] = bf16f(qa.x & 0xffffu); qs[1][ti] = bf16f(qa.x >> 16);
        qs[2][ti] = bf16f(qa.y & 0xffffu); qs[3][ti] = bf16f(qa.y >> 16);
        qs[4][ti] = bf16f(qb.x & 0xffffu); qs[5][ti] = bf16f(qb.x >> 16);
        qs[6][ti] = bf16f(qb.y & 0xffffu); qs[7][ti] = bf16f(qb.y >> 16);
    }
    __syncthreads();

    float vh[8], kh[8], km[8], vm[8];
    {
        uint2 a, c;
        a = VKM2[pb + (long)(0 + q0) * 1024 + tid];
        c = VKM2[pb + (long)(1 + q0) * 1024 + tid];
        vh[0]=bf16f(a.x&0xffffu); vh[1]=bf16f(a.x>>16); vh[2]=bf16f(a.y&0xffffu); vh[3]=bf16f(a.y>>16);
        vh[4]=bf16f(c.x&0xffffu); vh[5]=bf16f(c.x>>16); vh[6]=bf16f(c.y&0xffffu); vh[7]=bf16f(c.y>>16);
        a = VKM2[pb + (long)(32 + q0) * 1024 + tid];
        c = VKM2[pb + (long)(33 + q0) * 1024 + tid];
        kh[0]=bf16f(a.x&0xffffu); kh[1]=bf16f(a.x>>16); kh[2]=bf16f(a.y&0xffffu); kh[3]=bf16f(a.y>>16);
        kh[4]=bf16f(c.x&0xffffu); kh[5]=bf16f(c.x>>16); kh[6]=bf16f(c.y&0xffffu); kh[7]=bf16f(c.y>>16);
        a = VKM2[pb + (long)(96 + q0) * 1024 + tid];
        c = VKM2[pb + (long)(97 + q0) * 1024 + tid];
        km[0]=bf16f(a.x&0xffffu); km[1]=bf16f(a.x>>16); km[2]=bf16f(a.y&0xffffu); km[3]=bf16f(a.y>>16);
        km[4]=bf16f(c.x&0xffffu); km[5]=bf16f(c.x>>16); km[6]=bf16f(c.y&0xffffu); km[7]=bf16f(c.y>>16);
        a = VKM2[pb + (long)(128 + q0) * 1024 + tid];
        c = VKM2[pb + (long)(129 + q0) * 1024 + tid];
        vm[0]=bf16f(a.x&0xffffu); vm[1]=bf16f(a.x>>16); vm[2]=bf16f(a.y&0xffffu); vm[3]=bf16f(a.y>>16);
        vm[4]=bf16f(c.x&0xffffu); vm[5]=bf16f(c.x>>16); vm[6]=bf16f(c.y&0xffffu); vm[7]=bf16f(c.y>>16);
    }

    unsigned short zh[8], zm[8];
    const int ti = (tid >> 5) * 33 + (tid & 31);
    #pragma unroll
    for (int cc = 0; cc < 8; ++cc) {
        float qhT = qs[cc][ti];
        float sh = kh[cc] * qhT, sm = qhT * km[cc];
        float mh = sh, mm = sm;
        #pragma unroll
        for (int o = 16; o > 0; o >>= 1) {
            mh = fmaxf(mh, __shfl_xor(mh, o, 32));
            mm = fmaxf(mm, __shfl_xor(mm, o, 32));
        }
        float eh = __expf(sh - mh), em = __expf(sm - mm);
        float s1 = eh, s2 = em;
        #pragma unroll
        for (int o = 16; o > 0; o >>= 1) {
            s1 += __shfl_xor(s1, o, 32);
            s2 += __shfl_xor(s2, o, 32);
        }
        zh[cc] = pack_bf16(vh[cc] * (eh / s1));
        zm[cc] = pack_bf16(vm[cc] * (em / s2));
    }
    // zh at k=c0..c0+7 (ktile c0>>5), zm at k=c0+128 (ktile +4); 8 u16 = one uint4
    const int kt = c0 >> 5, kb = (c0 >> 3) & 3;
    const int phys = ((tid & 127) + (kb << 4)) & 127;
    long e16 = (long)b * WZ16 + ((long)((tid >> 7) * 8 + kt) << 12) +
               (kb << 10) + (phys << 3);
    uint4 oh, om;
    oh.x = (unsigned)zh[0] | ((unsigned)zh[1] << 16);
    oh.y = (unsigned)zh[2] | ((unsigned)zh[3] << 16);
    oh.z = (unsigned)zh[4] | ((unsigned)zh[5] << 16);
    oh.w = (unsigned)zh[6] | ((unsigned)zh[7] << 16);
    om.x = (unsigned)zm[0] | ((unsigned)zm[1] << 16);
    om.y = (unsigned)zm[2] | ((unsigned)zm[3] << 16);
    om.z = (unsigned)zm[4] | ((unsigned)zm[5] << 16);
    om.w = (unsigned)zm[6] | ((unsigned)zm[7] << 16);
    Zimg4[e16 >> 3]                 = oh;
    Zimg4[(e16 + (4l << 12)) >> 3]  = om;
}

// ---------------- pack x into v3 bf16 image: dest-linear streaming ----------------
// one thread = one uint4 = 8 u16 = one row's 8 channels of one kblock.
// x layout is [B][T][C][HW] (batch-major)
__global__ __launch_bounds__(256) void pack_x(
    const float* __restrict__ x, uint4* __restrict__ Xp, int tstart, int oneshot)
{
    long q = (long)blockIdx.x * 256 + threadIdx.x;
    long e = q << 3;                        // u16 index
    int t = tstart + (int)(e >> 21);
    long r = e & ((1l << 21) - 1);
    int b = (int)(r >> 17);
    int v = (int)(r & ((1 << 17) - 1));     // u16 within batch image
    int tile = v >> 12;                     // ptile*4 + ktile
    int pt = tile >> 2, kt = tile & 3;
    int ww = v & 4095;
    int kb = ww >> 10, phys = (ww >> 3) & 127;
    int row = (phys - (kb << 4)) & 127;
    int p = (pt << 7) + row;
    int c = (kt << 5) + (kb << 3);
    const float* xs = x + (((long)b * TT + t) * CC + c) * HW + p;
    union { unsigned short s[8]; uint4 u; } o;
    #pragma unroll
    for (int jj = 0; jj < 8; ++jj)
        o.s[jj] = pack_bf16(xs[(long)jj * HW]);
    Xp[oneshot ? q : (q & ((1l << 18) - 1))] = o.u;
}

// ---------------- one-shot setup: build v3 bf16 weight tile images ----------------
__device__ __forceinline__ void wimg(unsigned short* img, int Ktiles, int r, int k, float v) {
    int tile = (r >> 7) * Ktiles + (k >> 5);
    int row = r & 127, ks = k & 31;
    int kb = ks >> 3;
    int phys = (row + (kb << 4)) & 127;
    img[(size_t)tile * TW16 + (kb << 10) + (phys << 3) + (ks & 7)] = pack_bf16(v);
}

__global__ __launch_bounds__(256) void setup_all(
    const float* __restrict__ W5, const float* __restrict__ W8, const float* __restrict__ b8,
    unsigned short* __restrict__ Wp5i,
    unsigned short* __restrict__ Wgi, float* __restrict__ bg4,
    unsigned short* __restrict__ Woi, float* __restrict__ bo4)
{
    int idx = blockIdx.x * 256 + threadIdx.x;
    if (idx < 81920) {                       // W5 [640][128] -> Wp5 image (Ktiles=4)
        int r = idx >> 7, k = idx & 127;
        wimg(Wp5i, 4, r, k, W5[idx]);
        return;
    }
    idx -= 81920;
    if (idx < 131072) {                      // Wg: rows c*4+gate, convs 10..13, K=256 (Ktiles=8)
        int rr = idx >> 8, k = idx & 255;
        int c = rr >> 2, gg = rr & 3;
        wimg(Wgi, 8, rr, k, W8[((long)(4 + gg) * 128 + c) * 256 + k]);
        if (k == 0) bg4[rr] = b8[(4 + gg) * 128 + c];
        return;
    }
    idx -= 131072;                           // Wo: 512 rows x 384, conv6 folded (Ktiles=12)
    if (idx >= 512 * 384) return;
    int rr = idx / 384, k = idx - rr * 384;
    int c = rr >> 2, gg = rr & 3;
    float wv = 0.0f;
    if (gg < 3) {
        const float* wr = W8 + ((long)(1 + gg) * 128 + c) * 256;
        if (k < 128) {
            wv = wr[k];
        } else {
            int i = k - 128;
            float s = 0.0f;
            for (int j = 0; j < 128; ++j)
                s += wr[128 + j] * W8[(long)j * 256 + i];   // Wz = W8[0]
            wv = s;
        }
    }
    wimg(Woi, 12, rr, k, wv);
    if (k == 0) {
        float bb = 0.0f;
        if (gg < 3) {
            bb = b8[(1 + gg) * 128 + c];
            const float* wr = W8 + ((long)(1 + gg) * 128 + c) * 256;
            for (int j = 0; j < 128; ++j) bb += wr[128 + j] * b8[j];  // bz = b8[0]
        }
        bo4[rr] = bb;
    }
}

extern "C" void kernel_launch(void* const* d_in, const int* in_sizes, int n_in,
                              void* d_out, int out_size, void* d_ws, size_t ws_size,
                              hipStream_t stream)
{
    const float* x  = (const float*)d_in[0];   // [16][16][128][1024]  (B-major)
    const float* c0 = (const float*)d_in[1];
    const float* W5 = (const float*)d_in[2];   // [640][128]
    const float* b5 = (const float*)d_in[3];   // [640]
    const float* W8 = (const float*)d_in[4];   // [8][128][256]
    const float* b8 = (const float*)d_in[5];   // [8][128]
    float* out = (float*)d_out;

    const long S = STOT;
    unsigned short* Ha  = (unsigned short*)d_ws;        // 16*WI16 u16 image
    unsigned short* Hb  = Ha + 16l * WI16;              // 16*WI16
    unsigned short* mpi = Hb + 16l * WI16;              // 16*WI16 (mp bf16 image)
    float* mpf = (float*)(mpi + 16l * WI16);            // S fp32 (mp full state)
    float* Cst = mpf + S;                               // S fp32
    unsigned short* Wp5i = (unsigned short*)(Cst + S);  // 20 tiles * 4096 u16
    unsigned short* Wgi  = Wp5i + 20 * TW16;            // 32 tiles
    unsigned short* Woi  = Wgi + 32 * TW16;             // 48 tiles
    float* bg4 = (float*)(Woi + 48 * TW16);             // 512
    float* bo4 = bg4 + 512;                             // 512
    unsigned short* VKM  = (unsigned short*)(bo4 + 512);   // 5S u16, v2 layout
    unsigned short* Zimg = VKM + 5 * S;                    // 16*WZ16 u16 image
    unsigned short* Xp   = Zimg + 16l * WZ16;              // 16*XW16 full, or XW16 slot

    const bool havex =
        ((char*)(Xp + 16l * XW16) - (char*)d_ws) <= (long)ws_size;

    hipMemsetAsync(Hb,  0, 16l * WI16 * 2, stream);
    hipMemsetAsync(mpi, 0, 16l * WI16 * 2, stream);
    hipMemsetAsync(mpf, 0, S * sizeof(float), stream);
    hipMemcpyAsync(Cst, c0, S * sizeof(float), hipMemcpyDeviceToDevice, stream);

    setup_all<<<1600, dim3(256), 0, stream>>>(W5, W8, b8, Wp5i, Wgi, bg4, Woi, bo4);
    if (havex)
        pack_x<<<16384, dim3(256), 0, stream>>>(x, (uint4*)Xp, 0, 1);

    const int BIG = 1 << 30;
    const dim3 blk(256);
    for (int t = 0; t < TT; ++t) {
        if (!havex)
            pack_x<<<1024, dim3(256), 0, stream>>>(x, (uint4*)Xp, t, 0);
        const unsigned short* Xpt = Xp + (havex ? (long)t * XW16 : 0l);

        // gates = Wg * [Hb ; x_t], fused LSTM -> Cst, Ha image  (M=512, K=256)
        gemm_mfma<2><<<dim3(8, 4, 16), blk, 0, stream>>>(
            Wgi, bg4, Hb, (long)WI16, Xpt, (long)WI16, 4,
            128, BIG, Ha, Cst, nullptr, nullptr, 512, 256);

        // vh,kh,qh (Ha) + km,vm (mpi)   (M=640, K=128) -> VKM v2
        gemm_mfma<1><<<dim3(8, 5, 16), blk, 0, stream>>>(
            Wp5i, b5, Ha, (long)WI16, mpi, (long)WI16, 4,
            BIG, 384, VKM, nullptr, nullptr, nullptr, 640, 128);

        attn_kernel<<<256, dim3(1024), 0, stream>>>((const uint2*)VKM, (uint4*)Zimg);

        // o,g,i = Wo * [Ha ; Zimg] (conv6 folded), fused final -> mpf/mpi, Hb (+out)
        gemm_mfma<3><<<dim3(8, 4, 16), blk, 0, stream>>>(
            Woi, bo4, Ha, (long)WI16, Zimg, (long)WZ16, 8,
            128, BIG, Hb, mpf, mpi, (t == TT - 1) ? out : nullptr, 512, 384);
    }
}

// Round 14
// 1034.900 us; speedup vs baseline: 10.2755x; 1.0143x over previous
//
#include <hip/hip_runtime.h>
#include <hip/hip_bf16.h>

#define BB 16
#define TT 16
#define CC 128
#define HW 1024             // 32*32
#define PIX (CC*HW)         // 131072
#define STOT ((long)BB*PIX) // 2M

// image geometry v3 (A and B): tiles of 128 rows x 32 k, u16 bf16, kblock-major (8 ch),
// a16(row,k) = (k>>3)*1024 + phys*8 + (k&7), phys = (row + 16*(k>>3)) & 127
#define TW16 4096           // u16 per tile (8192 B)
#define WI16 131072         // u16 per batch, K=128 image (8 ptiles * 4 ktiles)
#define WZ16 262144         // u16 per batch, K=256 image (ZHZM)
#define XW16 2097152        // u16 per timestep of Xp (16 batches * WI16)
// VKM v2: u16 elem (b,row,p) at ((b*160 + (row>>2))*1024 + p)*4 + (row&3)

typedef short short8 __attribute__((ext_vector_type(8)));
typedef float f32x4  __attribute__((ext_vector_type(4)));

__device__ __forceinline__ float sigf(float x) { return 1.0f / (1.0f + __expf(-x)); }
__device__ __forceinline__ float tanhf_fast(float x) {
    float ax = fabsf(x);
    float t = __expf(-2.0f * ax);
    float r = (1.0f - t) / (1.0f + t);
    return copysignf(r, x);
}

__device__ __forceinline__ unsigned short pack_bf16(float x) {
    unsigned u = __float_as_uint(x);
    return (unsigned short)((u + 0x7fffu + ((u >> 16) & 1u)) >> 16);
}
__device__ __forceinline__ float bf16f(unsigned s) {
    return __uint_as_float(s << 16);
}

// u16 index of element (pixel p, k-channel c) in a per-batch v3 image with nkt k-tiles
__device__ __forceinline__ long bidx16(int p, int c, int nkt) {
    int kb = (c >> 3) & 3;
    int phys = ((p & 127) + (kb << 4)) & 127;
    return ((long)((p >> 7) * nkt + (c >> 5)) << 12) + (kb << 10) + (phys << 3) + (c & 7);
}

typedef __attribute__((address_space(3))) unsigned lds_u32_t;
typedef __attribute__((address_space(1))) const unsigned gbl_u32_t;
__device__ __forceinline__ void gld16(const void* g, unsigned* l) {
    __builtin_amdgcn_global_load_lds((gbl_u32_t*)g, (lds_u32_t*)l, 16, 0, 0);
}

// ---------------- MFMA GEMM, fused epilogues; 1-pass bf16, BK=64 double-buffered ----------------
// MODE 1: VKM v2 store (+ bias4[rq]) -> outv = uint2* (row-quad interleaved)
// MODE 2: LSTM fuse: stv=Cst(f32 linear), outv=Ha image (u16)
// MODE 3: final fuse: stv=mpl(bf16 linear), simg=mp image(u16), outv=Hb image(u16), Hout opt
// B-source per 32-chunk: m0>=m_split -> imgB(kofs 0); k>=k_split -> imgB(kofs k_split); else imgA.
// Pipeline: one barrier per 64-K iter; stage(it+1) DMA issued right after the barrier,
// in flight under this iter's 32 MFMA + ds_reads. K must be a multiple of 64.
template<int MODE>
__global__ __launch_bounds__(256, 2) void gemm_mfma(
    const unsigned short* __restrict__ Wp, const float* __restrict__ bias,
    const unsigned short* __restrict__ imgA, long wA,
    const unsigned short* __restrict__ imgB, long wB, int nktB,
    int k_split, int m_split,
    void* __restrict__ outv, void* __restrict__ stv,
    unsigned short* __restrict__ simg, float* __restrict__ Hout,
    int M, int K)
{
    __shared__ __align__(16) unsigned As[2][4096];   // 2 x 16 KB (two 8 KB k-chunks)
    __shared__ __align__(16) unsigned Bs[2][4096];   // 2 x 16 KB

    const int b  = blockIdx.z;
    const int n0 = blockIdx.x * 128;
    const int m0 = blockIdx.y * 128;
    const int t  = threadIdx.x;
    const int lane = t & 63;
    const int w  = t >> 6;
    const int wm = w & 1, wn = w >> 1;
    const int g  = lane >> 4, pl = lane & 15;
    const int nk64 = K >> 6;

    f32x4 acc[4][4] = {};

    auto stageA = [&](int kchunk, unsigned* dst) {
        const char* gA = (const char*)(Wp +
            (size_t)((m0 >> 7) * (K >> 5) + (kchunk >> 5)) * TW16);
        gld16(gA + t * 16, dst + t * 4);
        gld16(gA + 4096 + t * 16, dst + 1024 + t * 4);
    };
    auto stageB = [&](int kchunk, unsigned* dst) {
        const bool useB = (m0 >= m_split) || (kchunk >= k_split);
        const int kc = useB ? (kchunk - ((m0 >= m_split) ? 0 : k_split)) : kchunk;
        const unsigned short* img = useB ? imgB : imgA;
        const long bw = useB ? wB : wA;
        const int nkt = useB ? nktB : 4;
        const char* gB = (const char*)(img + (long)b * bw +
            ((long)((n0 >> 7) * nkt + (kc >> 5)) << 12));
        gld16(gB + t * 16, dst + t * 4);
        gld16(gB + 4096 + t * 16, dst + 1024 + t * 4);
    };
    auto stage = [&](int k0, int buf) {
        stageA(k0,      As[buf]);
        stageA(k0 + 32, As[buf] + 2048);
        stageB(k0,      Bs[buf]);
        stageB(k0 + 32, Bs[buf] + 2048);
    };

    stage(0, 0);                                   // prologue

    for (int it = 0; it < nk64; ++it) {
        const int buf = it & 1;
        __syncthreads();                           // drains stage(it); prev compute done
        if (it + 1 < nk64) stage((it + 1) << 6, buf ^ 1);   // DMA under MFMA

        #pragma unroll
        for (int h = 0; h < 2; ++h) {
            short8 afr[4], bfr[4];
            #pragma unroll
            for (int mt = 0; mt < 4; ++mt) {
                int row = 64 * wm + 16 * mt + pl;
                int phys = (row + (g << 4)) & 127;
                afr[mt] = *(const short8*)((const char*)As[buf] + h * 8192 + g * 2048 + phys * 16);
            }
            #pragma unroll
            for (int nt = 0; nt < 4; ++nt) {
                int prow = 64 * wn + 16 * nt + pl;
                int phys = (prow + (g << 4)) & 127;
                bfr[nt] = *(const short8*)((const char*)Bs[buf] + h * 8192 + g * 2048 + phys * 16);
            }
            #pragma unroll
            for (int mt = 0; mt < 4; ++mt)
                #pragma unroll
                for (int nt = 0; nt < 4; ++nt)
                    acc[mt][nt] = __builtin_amdgcn_mfma_f32_16x16x32_bf16(afr[mt], bfr[nt], acc[mt][nt], 0, 0, 0);
        }
    }

    if (MODE == 1) {
        // VKM v2: one dense uint2 per (mt,nt) — rows 4*rq..4*rq+3 at one column
        const float4* b4 = (const float4*)bias;
        uint2* V2 = (uint2*)outv;
        #pragma unroll
        for (int mt = 0; mt < 4; ++mt) {
            int rq = (m0 >> 2) + 16 * wm + 4 * mt + g;
            float4 bb = b4[rq];
            #pragma unroll
            for (int nt = 0; nt < 4; ++nt) {
                int col = n0 + 64 * wn + 16 * nt + pl;
                uint2 o;
                o.x = (unsigned)pack_bf16(acc[mt][nt][0] + bb.x) |
                      ((unsigned)pack_bf16(acc[mt][nt][1] + bb.y) << 16);
                o.y = (unsigned)pack_bf16(acc[mt][nt][2] + bb.z) |
                      ((unsigned)pack_bf16(acc[mt][nt][3] + bb.w) << 16);
                V2[((long)b * (M >> 2) + rq) * 1024 + col] = o;
            }
        }
    } else {
        // rows interleaved c*4+gate: one thread's f32x4 = all 4 gates of channel c
        const float4* bias4 = (const float4*)bias;
        unsigned short* Hp = (unsigned short*)outv;
        #pragma unroll
        for (int mt = 0; mt < 4; ++mt) {
            int c = (m0 >> 2) + 16 * wm + 4 * mt + g;
            float4 bb = bias4[c];
            #pragma unroll
            for (int nt = 0; nt < 4; ++nt) {
                int p = n0 + 64 * wn + 16 * nt + pl;
                long lidx = (long)b * PIX + (long)c * HW + p;       // linear (state)
                long widx = (long)b * WI16 + bidx16(p, c, 4);       // u16 image
                float v0 = acc[mt][nt][0] + bb.x;
                float v1 = acc[mt][nt][1] + bb.y;
                float v2 = acc[mt][nt][2] + bb.z;
                float v3 = acc[mt][nt][3] + bb.w;
                if (MODE == 2) {
                    float* Cst = (float*)stv;
                    float cc = Cst[lidx] * sigf(v0) + sigf(v1) * tanhf_fast(v2);
                    Cst[lidx] = cc;
                    Hp[widx] = pack_bf16(sigf(v3) * tanhf_fast(cc));
                } else {
                    unsigned short* mpl = (unsigned short*)stv;     // bf16 linear state
                    float ot = sigf(v0), gt = tanhf_fast(v1), it2 = sigf(v2);
                    float mo = bf16f(mpl[lidx]);
                    float mn = gt * it2 + (1.0f - it2) * mo;
                    unsigned short mw = pack_bf16(mn);
                    mpl[lidx] = mw;
                    simg[widx] = mw;
                    float hv = ot * mn;
                    Hp[widx] = pack_bf16(hv);
                    if (Hout) Hout[lidx] = hv;
                }
            }
        }
    }
}

// ---------------- attention: VKM v2 (uint2) -> Zimg v3 (uint4) ----------------
// block = (b, c-oct): 8 channels per block; dense uint2 loads, dense uint4 stores.
// planes (rq base): vh=0, kh=32, qh=64, km=96, vm=128 (+q0, q0 = c0>>2)
__global__ __launch_bounds__(1024) void attn_kernel(
    const uint2* __restrict__ VKM2, uint4* __restrict__ Zimg4)
{
    __shared__ float qs[8][32 * 33];
    const int tid = threadIdx.x;
    const int b = blockIdx.x >> 4, c8 = blockIdx.x & 15;
    const int c0 = c8 << 3;
    const int q0 = c8 << 1;
    const long pb = (long)b * 160 * 1024;

    // stage qh^T for 8 channels
    {
        uint2 qa = VKM2[pb + (long)(64 + q0) * 1024 + tid];
        uint2 qb = VKM2[pb + (long)(65 + q0) * 1024 + tid];
        int ti = (tid & 31) * 33 + (tid >> 5);
        qs[0][ti] = bf16f(qa.x & 0xffffu); qs[1][ti] = bf16f(qa.x >> 16);
        qs[2][ti] = bf16f(qa.y & 0xffffu); qs[3][ti] = bf16f(qa.y >> 16);
        qs[4][ti] = bf16f(qb.x & 0xffffu); qs[5][ti] = bf16f(qb.x >> 16);
        qs[6][ti] = bf16f(qb.y & 0xffffu); qs[7][ti] = bf16f(qb.y >> 16);
    }
    __syncthreads();

    float vh[8], kh[8], km[8], vm[8];
    {
        uint2 a, c;
        a = VKM2[pb + (long)(0 + q0) * 1024 + tid];
        c = VKM2[pb + (long)(1 + q0) * 1024 + tid];
        vh[0]=bf16f(a.x&0xffffu); vh[1]=bf16f(a.x>>16); vh[2]=bf16f(a.y&0xffffu); vh[3]=bf16f(a.y>>16);
        vh[4]=bf16f(c.x&0xffffu); vh[5]=bf16f(c.x>>16); vh[6]=bf16f(c.y&0xffffu); vh[7]=bf16f(c.y>>16);
        a = VKM2[pb + (long)(32 + q0) * 1024 + tid];
        c = VKM2[pb + (long)(33 + q0) * 1024 + tid];
        kh[0]=bf16f(a.x&0xffffu); kh[1]=bf16f(a.x>>16); kh[2]=bf16f(a.y&0xffffu); kh[3]=bf16f(a.y>>16);
        kh[4]=bf16f(c.x&0xffffu); kh[5]=bf16f(c.x>>16); kh[6]=bf16f(c.y&0xffffu); kh[7]=bf16f(c.y>>16);
        a = VKM2[pb + (long)(96 + q0) * 1024 + tid];
        c = VKM2[pb + (long)(97 + q0) * 1024 + tid];
        km[0]=bf16f(a.x&0xffffu); km[1]=bf16f(a.x>>16); km[2]=bf16f(a.y&0xffffu); km[3]=bf16f(a.y>>16);
        km[4]=bf16f(c.x&0xffffu); km[5]=bf16f(c.x>>16); km[6]=bf16f(c.y&0xffffu); km[7]=bf16f(c.y>>16);
        a = VKM2[pb + (long)(128 + q0) * 1024 + tid];
        c = VKM2[pb + (long)(129 + q0) * 1024 + tid];
        vm[0]=bf16f(a.x&0xffffu); vm[1]=bf16f(a.x>>16); vm[2]=bf16f(a.y&0xffffu); vm[3]=bf16f(a.y>>16);
        vm[4]=bf16f(c.x&0xffffu); vm[5]=bf16f(c.x>>16); vm[6]=bf16f(c.y&0xffffu); vm[7]=bf16f(c.y>>16);
    }

    unsigned short zh[8], zm[8];
    const int ti = (tid >> 5) * 33 + (tid & 31);
    #pragma unroll
    for (int cc = 0; cc < 8; ++cc) {
        float qhT = qs[cc][ti];
        float sh = kh[cc] * qhT, sm = qhT * km[cc];
        float mh = sh, mm = sm;
        #pragma unroll
        for (int o = 16; o > 0; o >>= 1) {
            mh = fmaxf(mh, __shfl_xor(mh, o, 32));
            mm = fmaxf(mm, __shfl_xor(mm, o, 32));
        }
        float eh = __expf(sh - mh), em = __expf(sm - mm);
        float s1 = eh, s2 = em;
        #pragma unroll
        for (int o = 16; o > 0; o >>= 1) {
            s1 += __shfl_xor(s1, o, 32);
            s2 += __shfl_xor(s2, o, 32);
        }
        zh[cc] = pack_bf16(vh[cc] * (eh / s1));
        zm[cc] = pack_bf16(vm[cc] * (em / s2));
    }
    // zh at k=c0..c0+7 (ktile c0>>5), zm at k=c0+128 (ktile +4); 8 u16 = one uint4
    const int kt = c0 >> 5, kb = (c0 >> 3) & 3;
    const int phys = ((tid & 127) + (kb << 4)) & 127;
    long e16 = (long)b * WZ16 + ((long)((tid >> 7) * 8 + kt) << 12) +
               (kb << 10) + (phys << 3);
    uint4 oh, om;
    oh.x = (unsigned)zh[0] | ((unsigned)zh[1] << 16);
    oh.y = (unsigned)zh[2] | ((unsigned)zh[3] << 16);
    oh.z = (unsigned)zh[4] | ((unsigned)zh[5] << 16);
    oh.w = (unsigned)zh[6] | ((unsigned)zh[7] << 16);
    om.x = (unsigned)zm[0] | ((unsigned)zm[1] << 16);
    om.y = (unsigned)zm[2] | ((unsigned)zm[3] << 16);
    om.z = (unsigned)zm[4] | ((unsigned)zm[5] << 16);
    om.w = (unsigned)zm[6] | ((unsigned)zm[7] << 16);
    Zimg4[e16 >> 3]                 = oh;
    Zimg4[(e16 + (4l << 12)) >> 3]  = om;
}

// ---------------- pack x into v3 bf16 image: vectorized dest-linear streaming ----------------
// one thread = 4 consecutive dest uint4 (32 u16 = 8 channels x 4 pixels);
// reads 8 float4 (1 KB/wave per load instr), register 8x4 transpose, 64 B/thread stores.
// x layout is [B][T][C][HW] (batch-major)
__global__ __launch_bounds__(256) void pack_x(
    const float* __restrict__ x, uint4* __restrict__ Xp, int tstart, int oneshot)
{
    long q = (long)blockIdx.x * 256 + threadIdx.x;   // quad-of-uint4 index
    long e = q << 5;                        // u16 index (32 per thread)
    int t = tstart + (int)(e >> 21);
    long r = e & ((1l << 21) - 1);
    int b = (int)(r >> 17);
    int v = (int)(r & ((1 << 17) - 1));     // u16 within batch image (32-aligned)
    int tile = v >> 12;                     // ptile*4 + ktile
    int pt = tile >> 2, kt = tile & 3;
    int ww = v & 4095;
    int kb = ww >> 10, phys = (ww >> 3) & 127;   // phys 4-aligned
    int row = (phys - (kb << 4)) & 127;          // 4 consecutive rows, no wrap
    int p = (pt << 7) + row;
    int c = (kt << 5) + (kb << 3);
    const float* xs = x + (((long)b * TT + t) * CC + c) * HW + p;
    float4 f[8];
    #pragma unroll
    for (int jj = 0; jj < 8; ++jj)
        f[jj] = *(const float4*)(xs + (long)jj * HW);
    uint4* dst = Xp + (oneshot ? (q << 2) : ((q << 2) & ((1l << 18) - 1)));
    #pragma unroll
    for (int i = 0; i < 4; ++i) {
        union { unsigned short s[8]; uint4 u; } o;
        #pragma unroll
        for (int jj = 0; jj < 8; ++jj)
            o.s[jj] = pack_bf16(((const float*)&f[jj])[i]);
        dst[i] = o.u;
    }
}

// ---------------- one-shot setup: build v3 bf16 weight tile images ----------------
__device__ __forceinline__ void wimg(unsigned short* img, int Ktiles, int r, int k, float v) {
    int tile = (r >> 7) * Ktiles + (k >> 5);
    int row = r & 127, ks = k & 31;
    int kb = ks >> 3;
    int phys = (row + (kb << 4)) & 127;
    img[(size_t)tile * TW16 + (kb << 10) + (phys << 3) + (ks & 7)] = pack_bf16(v);
}

__global__ __launch_bounds__(256) void setup_all(
    const float* __restrict__ W5, const float* __restrict__ W8, const float* __restrict__ b8,
    unsigned short* __restrict__ Wp5i,
    unsigned short* __restrict__ Wgi, float* __restrict__ bg4,
    unsigned short* __restrict__ Woi, float* __restrict__ bo4)
{
    int idx = blockIdx.x * 256 + threadIdx.x;
    if (idx < 81920) {                       // W5 [640][128] -> Wp5 image (Ktiles=4)
        int r = idx >> 7, k = idx & 127;
        wimg(Wp5i, 4, r, k, W5[idx]);
        return;
    }
    idx -= 81920;
    if (idx < 131072) {                      // Wg: rows c*4+gate, convs 10..13, K=256 (Ktiles=8)
        int rr = idx >> 8, k = idx & 255;
        int c = rr >> 2, gg = rr & 3;
        wimg(Wgi, 8, rr, k, W8[((long)(4 + gg) * 128 + c) * 256 + k]);
        if (k == 0) bg4[rr] = b8[(4 + gg) * 128 + c];
        return;
    }
    idx -= 131072;                           // Wo: 512 rows x 384, conv6 folded (Ktiles=12)
    if (idx >= 512 * 384) return;
    int rr = idx / 384, k = idx - rr * 384;
    int c = rr >> 2, gg = rr & 3;
    float wv = 0.0f;
    if (gg < 3) {
        const float* wr = W8 + ((long)(1 + gg) * 128 + c) * 256;
        if (k < 128) {
            wv = wr[k];
        } else {
            int i = k - 128;
            float s = 0.0f;
            for (int j = 0; j < 128; ++j)
                s += wr[128 + j] * W8[(long)j * 256 + i];   // Wz = W8[0]
            wv = s;
        }
    }
    wimg(Woi, 12, rr, k, wv);
    if (k == 0) {
        float bb = 0.0f;
        if (gg < 3) {
            bb = b8[(1 + gg) * 128 + c];
            const float* wr = W8 + ((long)(1 + gg) * 128 + c) * 256;
            for (int j = 0; j < 128; ++j) bb += wr[128 + j] * b8[j];  // bz = b8[0]
        }
        bo4[rr] = bb;
    }
}

extern "C" void kernel_launch(void* const* d_in, const int* in_sizes, int n_in,
                              void* d_out, int out_size, void* d_ws, size_t ws_size,
                              hipStream_t stream)
{
    const float* x  = (const float*)d_in[0];   // [16][16][128][1024]  (B-major)
    const float* c0 = (const float*)d_in[1];
    const float* W5 = (const float*)d_in[2];   // [640][128]
    const float* b5 = (const float*)d_in[3];   // [640]
    const float* W8 = (const float*)d_in[4];   // [8][128][256]
    const float* b8 = (const float*)d_in[5];   // [8][128]
    float* out = (float*)d_out;

    const long S = STOT;
    unsigned short* Ha  = (unsigned short*)d_ws;        // 16*WI16 u16 image
    unsigned short* Hb  = Ha + 16l * WI16;              // 16*WI16
    unsigned short* mpi = Hb + 16l * WI16;              // 16*WI16 (mp bf16 image)
    unsigned short* mpl = mpi + 16l * WI16;             // S u16 (mp bf16 linear state)
    float* Cst = (float*)(mpl + S);                     // S fp32
    unsigned short* Wp5i = (unsigned short*)(Cst + S);  // 20 tiles * 4096 u16
    unsigned short* Wgi  = Wp5i + 20 * TW16;            // 32 tiles
    unsigned short* Woi  = Wgi + 32 * TW16;             // 48 tiles
    float* bg4 = (float*)(Woi + 48 * TW16);             // 512
    float* bo4 = bg4 + 512;                             // 512
    unsigned short* VKM  = (unsigned short*)(bo4 + 512);   // 5S u16, v2 layout
    unsigned short* Zimg = VKM + 5 * S;                    // 16*WZ16 u16 image
    unsigned short* Xp   = Zimg + 16l * WZ16;              // 16*XW16 full, or XW16 slot

    const bool havex =
        ((char*)(Xp + 16l * XW16) - (char*)d_ws) <= (long)ws_size;

    hipMemsetAsync(Hb,  0, 16l * WI16 * 2, stream);
    hipMemsetAsync(mpi, 0, 16l * WI16 * 2, stream);
    hipMemsetAsync(mpl, 0, S * 2, stream);
    hipMemcpyAsync(Cst, c0, S * sizeof(float), hipMemcpyDeviceToDevice, stream);

    setup_all<<<1600, dim3(256), 0, stream>>>(W5, W8, b8, Wp5i, Wgi, bg4, Woi, bo4);
    if (havex)
        pack_x<<<4096, dim3(256), 0, stream>>>(x, (uint4*)Xp, 0, 1);

    const int BIG = 1 << 30;
    const dim3 blk(256);
    for (int t = 0; t < TT; ++t) {
        if (!havex)
            pack_x<<<256, dim3(256), 0, stream>>>(x, (uint4*)Xp, t, 0);
        const unsigned short* Xpt = Xp + (havex ? (long)t * XW16 : 0l);

        // gates = Wg * [Hb ; x_t], fused LSTM -> Cst, Ha image  (M=512, K=256)
        gemm_mfma<2><<<dim3(8, 4, 16), blk, 0, stream>>>(
            Wgi, bg4, Hb, (long)WI16, Xpt, (long)WI16, 4,
            128, BIG, Ha, Cst, nullptr, nullptr, 512, 256);

        // vh,kh,qh (Ha) + km,vm (mpi)   (M=640, K=128) -> VKM v2
        gemm_mfma<1><<<dim3(8, 5, 16), blk, 0, stream>>>(
            Wp5i, b5, Ha, (long)WI16, mpi, (long)WI16, 4,
            BIG, 384, VKM, nullptr, nullptr, nullptr, 640, 128);

        attn_kernel<<<256, dim3(1024), 0, stream>>>((const uint2*)VKM, (uint4*)Zimg);

        // o,g,i = Wo * [Ha ; Zimg] (conv6 folded), fused final -> mpl/mpi, Hb (+out)
        gemm_mfma<3><<<dim3(8, 4, 16), blk, 0, stream>>>(
            Woi, bo4, Ha, (long)WI16, Zimg, (long)WZ16, 8,
            128, BIG, Hb, mpl, mpi, (t == TT - 1) ? out : nullptr, 512, 384);
    }
}